// Round 13
// baseline (438.592 us; speedup 1.0000x reference)
//
#include <hip/hip_runtime.h>

// LoRA multi-head attention forward, B=2 S=2048 D=2048 H=16 dk=128 rank=8.
// Device dtype auto-detected (bf16 vs fp32) -> flag in ws; internal compute bf16.
// Pipeline: detect -> [prep effW^T -> GEMM] x3 (Q,K,V) -> V transpose ->
// causal flash attention -> prep effWo^T -> output GEMM.
// R13: attn triangle-PAIRED blocks (q-tiles x and 31-x per block -> constant
// 33 tile-units/block, 512 blocks == resident slots, no tail) + V read direct
// from global (L2-resident; Vs staging deleted, LDS 33KB).  GEMM = R9.

#define B_   2
#define S_   2048
#define D_   2048
#define H_   16
#define DK_  128
#define MROWS (B_*S_)            // 4096
#define SCALE_ 0.08838834764831845f   // 1/sqrt(128)

using f32x4 = __attribute__((ext_vector_type(4))) float;
using s16x8 = __attribute__((ext_vector_type(8))) short;
typedef unsigned short u16;
typedef unsigned int u32;

__device__ __forceinline__ float b2f(u16 u){ union{unsigned u32v; float f;} x; x.u32v=((unsigned)u)<<16; return x.f; }
__device__ __forceinline__ u16 f2b(float f){ union{float f; unsigned u;} x; x.f=f; unsigned r=x.u+0x7fffu+((x.u>>16)&1u); return (u16)(r>>16); }
__device__ __forceinline__ u32 pk2(float lo, float hi){
  return ((u32)f2b(hi) << 16) | (u32)f2b(lo);
}

__device__ __forceinline__ void glds16(const void* g, void* l){
  __builtin_amdgcn_global_load_lds((const __attribute__((address_space(1))) unsigned int*)g,
                                   (__attribute__((address_space(3))) unsigned int*)l, 16, 0, 0);
}

// ---------------------------------------------------------------------------
__global__ void detect32(const unsigned* __restrict__ q, int* __restrict__ flag)
{
  __shared__ int s[4];
  int c = 0;
  for (int i = threadIdx.x; i < 4096; i += 256){
    unsigned u = q[i];
    unsigned e0 = (u >> 7) & 0xFFu;
    if (e0 >= 0x90u) ++c;
  }
  #pragma unroll
  for (int off = 32; off; off >>= 1) c += __shfl_down(c, off);
  if ((threadIdx.x & 63) == 0) s[threadIdx.x >> 6] = c;
  __syncthreads();
  if (threadIdx.x == 0) *flag = ((s[0]+s[1]+s[2]+s[3]) > 64) ? 1 : 0;
}

// ---------------------------------------------------------------------------
// effWT[n][k] = w[k][n] + sum_r la[k][r]*lb[r][n]
__global__ __launch_bounds__(256) void prep_wt(const void* __restrict__ w_, const void* __restrict__ la_,
                                               const void* __restrict__ lb_, u16* __restrict__ wt,
                                               const int* __restrict__ flagp)
{
  const int f32i = *flagp;
  __shared__ float tile[64][65];
  const int tid = threadIdx.x;
  const int k0 = blockIdx.x*64, n0 = blockIdx.y*64;
  const int c  = tid & 63;
  const int r0 = (tid >> 6) * 16;
  float lbv[8];
  if (f32i){
    const float* lb = (const float*)lb_;
    #pragma unroll
    for (int r=0;r<8;++r) lbv[r] = lb[(size_t)r*D_ + n0 + c];
  } else {
    const u16* lb = (const u16*)lb_;
    #pragma unroll
    for (int r=0;r<8;++r) lbv[r] = b2f(lb[(size_t)r*D_ + n0 + c]);
  }
  #pragma unroll
  for (int kk=0;kk<16;++kk){
    const int k = k0 + r0 + kk;
    float val;
    if (f32i){
      const float* w32 = (const float*)w_;  const float* la = (const float*)la_;
      val = w32[(size_t)k*D_ + n0 + c];
      f32x4 a0 = *(const f32x4*)(la + k*8);
      f32x4 a1 = *(const f32x4*)(la + k*8 + 4);
      #pragma unroll
      for (int r=0;r<4;++r) val += a0[r]*lbv[r];
      #pragma unroll
      for (int r=0;r<4;++r) val += a1[r]*lbv[4+r];
    } else {
      const u16* w16 = (const u16*)w_;  const u16* la = (const u16*)la_;
      val = b2f(w16[(size_t)k*D_ + n0 + c]);
      s16x8 av = *(const s16x8*)(la + k*8);
      #pragma unroll
      for (int r=0;r<8;++r) val += b2f((u16)av[r])*lbv[r];
    }
    tile[r0+kk][c] = val;
  }
  __syncthreads();
  #pragma unroll
  for (int nn=0;nn<16;++nn){
    const int nr = r0 + nn;
    wt[(size_t)(n0+nr)*D_ + k0 + c] = f2b(tile[c][nr]);
  }
}

// ---------------------------------------------------------------------------
__global__ __launch_bounds__(256) void transpose_v(const u16* __restrict__ V, u16* __restrict__ VT)
{
  __shared__ u16 tile[64][66];
  const int bz = blockIdx.z;
  const int s0 = blockIdx.x*64, d0 = blockIdx.y*64;
  const int tid = threadIdx.x;
  const u16* Vb = V + (size_t)bz*S_*D_;
  u16* VTb = VT + (size_t)bz*D_*S_;
  const int c = tid & 63, r0 = (tid>>6)*16;
  #pragma unroll
  for (int i=0;i<16;++i) tile[r0+i][c] = Vb[(size_t)(s0+r0+i)*D_ + d0 + c];
  __syncthreads();
  #pragma unroll
  for (int i=0;i<16;++i) VTb[(size_t)(d0+r0+i)*S_ + s0 + c] = tile[c][r0+i];
}

// ---------------------------------------------------------------------------
// C[m][n] = sum_k A[m][k]*BT[n][k] + bias[n].  M=4096, N=K=2048.
// 128x128 tile, BK=64, double-buffered prefetch, one barrier/iter.
// Swizzle invariant: LDS[row][c] = global[row][c ^ ((row&7)<<3)] (u16 units).
__global__ __launch_bounds__(256) void gemm_bt(const void* __restrict__ A_, const u16* __restrict__ BT,
                                               const void* __restrict__ bias_, void* __restrict__ C_,
                                               const int* __restrict__ flagp, int aF, int oF)
{
  constexpr int N = D_, K = D_;
  constexpr int NT = K/64;
  const int f = *flagp;
  const bool a32 = (aF != 0) && (f != 0);
  const bool o32 = (oF != 0) && (f != 0);
  __shared__ u16 As[2][128*64];      // 32 KB
  __shared__ u16 Bs[2][128*64];      // 32 KB
  const int tid = threadIdx.x;
  const int w = tid>>6, lane = tid&63, g = lane>>4, lr = lane&15;
  const int wm = w>>1, wn = w&1;
  const int m0 = blockIdx.y*128, n0 = blockIdx.x*128;
  const int srow = lane>>3;                        // 0..7
  const int lcol = (lane&7)*8;                     // linear col, u16 units
  const int scol = lcol ^ (srow<<3);               // swizzled col
  const int rsw  = (lr&7)<<3;                      // read-side swizzle (u16)

  const float* Af = (const float*)A_;
  const u16*   Ab = (const u16*)A_;

  #define STAGE_B16(buf, k0_) do{ _Pragma("unroll")                                 \
    for (int jj=0;jj<4;++jj){ const int rb = w*32 + jj*8;                           \
      glds16(BT + (size_t)(n0+rb+srow)*K + (k0_) + scol, (void*)(&Bs[buf][0] + rb*64)); } }while(0)
  #define STAGE_A16(buf, k0_) do{ _Pragma("unroll")                                 \
    for (int jj=0;jj<4;++jj){ const int rb = w*32 + jj*8;                           \
      glds16(Ab + (size_t)(m0+rb+srow)*K + (k0_) + scol, (void*)(&As[buf][0] + rb*64)); } }while(0)
  #define LOAD_A32(k0_) do{ _Pragma("unroll")                                       \
    for (int jj=0;jj<4;++jj){                                                       \
      const float* src = Af + (size_t)(m0 + w*32 + jj*8 + srow)*K + (k0_) + lcol;   \
      ax0[jj] = *(const f32x4*)src; ax1[jj] = *(const f32x4*)(src + 4); } }while(0)
  #define WRITE_A32(buf) do{ _Pragma("unroll")                                      \
    for (int jj=0;jj<4;++jj){ const int rb = w*32 + jj*8; s16x8 pk;                 \
      _Pragma("unroll")                                                             \
      for (int i=0;i<4;++i){ pk[i]=(short)f2b(ax0[jj][i]); pk[4+i]=(short)f2b(ax1[jj][i]); } \
      *(s16x8*)(&As[buf][0] + (rb+srow)*64 + scol) = pk; } }while(0)

  f32x4 ax0[4], ax1[4];
  f32x4 acc[4][4] = {};

  if (a32){ LOAD_A32(0); WRITE_A32(0); } else { STAGE_A16(0, 0); }
  STAGE_B16(0, 0);
  __syncthreads();

  int cur = 0;
  for (int t=0; t<NT; ++t){
    const bool haveNext = (t+1 < NT);
    if (haveNext){
      if (a32) LOAD_A32((t+1)*64);              // issue early; write after compute
      else     STAGE_A16(cur^1, (t+1)*64);
      STAGE_B16(cur^1, (t+1)*64);
    }
    #pragma unroll
    for (int kk=0;kk<2;++kk){
      s16x8 af[4], bfr[4];
      #pragma unroll
      for (int i=0;i<4;++i) af[i]  = *(const s16x8*)(&As[cur][0] + (wm*64+i*16+lr)*64 + ((kk*32 + g*8) ^ rsw));
      #pragma unroll
      for (int i=0;i<4;++i) bfr[i] = *(const s16x8*)(&Bs[cur][0] + (wn*64+i*16+lr)*64 + ((kk*32 + g*8) ^ rsw));
      #pragma unroll
      for (int mi=0;mi<4;++mi)
        #pragma unroll
        for (int ni=0;ni<4;++ni)
          acc[mi][ni] = __builtin_amdgcn_mfma_f32_16x16x32_bf16(af[mi], bfr[ni], acc[mi][ni], 0,0,0);
    }
    if (haveNext && a32) WRITE_A32(cur^1);      // vmcnt wait lands after MFMAs
    __syncthreads();
    cur ^= 1;
  }
  #pragma unroll
  for (int ni=0;ni<4;++ni){
    const int n = n0 + wn*64 + ni*16 + lr;
    const float bv = f ? ((const float*)bias_)[n] : b2f(((const u16*)bias_)[n]);
    #pragma unroll
    for (int mi=0;mi<4;++mi){
      const int m = m0 + wm*64 + mi*16 + 4*g;
      #pragma unroll
      for (int r=0;r<4;++r){
        const float val = acc[mi][ni][r] + bv;
        if (o32) ((float*)C_)[(size_t)(m+r)*N + n] = val;
        else     ((u16*)C_)[(size_t)(m+r)*N + n] = f2b(val);
      }
    }
  }
  #undef STAGE_B16
  #undef STAGE_A16
  #undef LOAD_A32
  #undef WRITE_A32
}

// ---------------------------------------------------------------------------
// Causal flash attention.  grid (S/128, H, B), block 256 (4 waves x 16 q-rows).
// PAIRED blocks: block x handles q-tiles x and 31-x -> 33 tile-units constant.
// K staged in LDS (dbuf, XOR swizzle, 1 barrier/tile); V read DIRECT from
// global VT (L2-resident).  Swapped QK^T, lane-local softmax (q=lr), f2b pack
// + 16-shfl gather, ones-MFMA l-sum, defer-max THR=8.
__global__ __launch_bounds__(256) void attn(const u16* __restrict__ Q, const u16* __restrict__ K,
                                            const u16* __restrict__ VT, u16* __restrict__ O)
{
  __shared__ u16  Ks[2][64*128];     // 32 KB, rows kv (256B), swizzled
  u16 (*Ol)[16][136] = (u16(*)[16][136])(&Ks[0][0]);   // epilogue alias, dead staging

  const int tid = threadIdx.x;
  const int w = tid>>6, lane = tid&63, g = lane>>4, lr = lane&15;
  const int h = blockIdx.y, bz = blockIdx.z;
  const u16* Qb  = Q  + (size_t)bz*S_*D_;
  const u16* Kb  = K  + (size_t)bz*S_*D_;
  const u16* Vh  = VT + (size_t)bz*D_*S_ + (size_t)h*DK_*S_;   // V^T rows d, cols s
  u16* Ob = O + (size_t)bz*S_*D_;
  const int sw = (lr&7)<<4;                 // read-side swizzle (bytes)
  const int krow_l = lane>>4, kcol_l = (lane&15)*16;   // K staging lane map

  s16x8 ones;
  #pragma unroll
  for (int i=0;i<8;++i) ones[i] = (short)0x3F80;       // bf16 1.0

  #define STAGE_K(buf, t_) do{ const int kv0s = (t_)*64;                            \
    _Pragma("unroll")                                                               \
    for (int jj=0;jj<4;++jj){ const int j = w*4 + jj; const int r = j*4 + krow_l;   \
      const int cb = kcol_l ^ ((r&7)<<4);                                           \
      glds16(Kb + (size_t)(kv0s + r)*D_ + h*DK_ + (cb>>1), (void*)(&Ks[buf][0] + j*512)); } }while(0)

  for (int qq=0; qq<2; ++qq){
    const int qt = qq ? (int)(S_/64 - 1 - blockIdx.x) : (int)blockIdx.x;
    const int q0 = qt*64 + w*16;
    const int nt = qt + 1;

    // Q fragments, pre-scaled by 1/sqrt(dk)
    s16x8 qf[4];
    #pragma unroll
    for (int dc=0;dc<4;++dc){
      s16x8 t = *(const s16x8*)(Qb + (size_t)(q0+lr)*D_ + h*DK_ + dc*32 + g*8);
      #pragma unroll
      for (int i=0;i<8;++i) t[i] = (short)f2b(b2f((u16)t[i]) * SCALE_);
      qf[dc] = t;
    }
    float m_  = -1e30f;              // running max for q-row lr (lane-local)
    float l_q = 0.f;                 // row-sum for q-row lr (lane-local)
    f32x4 accO[8] = {};              // O^T[d=dt*16+4g+r][q=lr], fp32

    STAGE_K(0, 0);
    __syncthreads();
    int cur = 0;
    for (int t=0;t<nt;++t){
      const int kv0 = t*64;
      const bool lastT = (t == nt-1);
      if (!lastT) STAGE_K(cur^1, t+1);
      // --- QK^T (swapped): sacc[kt][r] = S[q=lr][key=kt*16+4g+r] ---
      const u16* Ksc = &Ks[cur][0];
      f32x4 sacc[4] = {};
      __builtin_amdgcn_s_setprio(1);
      #pragma unroll
      for (int dc=0;dc<4;++dc){
        const int cb = (dc*64 + g*16) ^ sw;
        #pragma unroll
        for (int kt=0;kt<4;++kt){
          s16x8 kf = *(const s16x8*)(Ksc + (kt*16+lr)*128 + (cb>>1));
          sacc[kt] = __builtin_amdgcn_mfma_f32_16x16x32_bf16(kf, qf[dc], sacc[kt], 0,0,0);
        }
      }
      __builtin_amdgcn_s_setprio(0);
      // --- V fragments direct from global (L2-resident); issue early so the
      //     ~200cy L2 latency hides under softmax VALU ---
      s16x8 vfr[16];
      #pragma unroll
      for (int dt=0;dt<8;++dt){
        const u16* vrow = Vh + (size_t)(dt*16+lr)*S_ + kv0 + g*8;
        vfr[2*dt]   = *(const s16x8*)(vrow);
        vfr[2*dt+1] = *(const s16x8*)(vrow + 32);
      }
      if (lastT){
        #pragma unroll
        for (int kt=0;kt<4;++kt)
          #pragma unroll
          for (int r=0;r<4;++r)
            if (kv0 + kt*16 + 4*g + r > q0 + lr) sacc[kt][r] = -1e30f;
      }
      // --- lane-local online softmax (q=lr), defer-max THR=8 ---
      float tm = sacc[0][0];
      #pragma unroll
      for (int kt=0;kt<4;++kt)
        #pragma unroll
        for (int r=0;r<4;++r) tm = fmaxf(tm, sacc[kt][r]);
      tm = fmaxf(tm, __shfl_xor(tm, 16));
      tm = fmaxf(tm, __shfl_xor(tm, 32));
      const float mn = (tm <= m_ + 8.f) ? m_ : tm;   // defer small growth
      const float sc = __expf(m_ - mn);              // ==1 when deferred
      m_ = mn;
      #pragma unroll
      for (int kt=0;kt<4;++kt)
        #pragma unroll
        for (int r=0;r<4;++r) sacc[kt][r] = __expf(sacc[kt][r] - mn);
      // --- pack P to bf16 pairs (f2b) and gather B-operand fragments ---
      u32 pa[4], pb[4];
      #pragma unroll
      for (int kt=0;kt<4;++kt){
        pa[kt] = pk2(sacc[kt][0], sacc[kt][1]);
        pb[kt] = pk2(sacc[kt][2], sacc[kt][3]);
      }
      const int srcA = lr + 32*(g&1);
      const int srcB = srcA + 16;
      const bool hi = (g >= 2);
      union { s16x8 v; u32 u[4]; } P0, P1;
      {
        u32 a0 = (u32)__shfl((int)pa[0], srcA), a1 = (u32)__shfl((int)pa[1], srcA);
        u32 b0 = (u32)__shfl((int)pb[0], srcA), b1 = (u32)__shfl((int)pb[1], srcA);
        u32 c0 = (u32)__shfl((int)pa[0], srcB), c1 = (u32)__shfl((int)pa[1], srcB);
        u32 d0 = (u32)__shfl((int)pb[0], srcB), d1 = (u32)__shfl((int)pb[1], srcB);
        P0.u[0] = hi ? a1 : a0;  P0.u[1] = hi ? b1 : b0;
        P0.u[2] = hi ? c1 : c0;  P0.u[3] = hi ? d1 : d0;
      }
      {
        u32 a0 = (u32)__shfl((int)pa[2], srcA), a1 = (u32)__shfl((int)pa[3], srcA);
        u32 b0 = (u32)__shfl((int)pb[2], srcA), b1 = (u32)__shfl((int)pb[3], srcA);
        u32 c0 = (u32)__shfl((int)pa[2], srcB), c1 = (u32)__shfl((int)pa[3], srcB);
        u32 d0 = (u32)__shfl((int)pb[2], srcB), d1 = (u32)__shfl((int)pb[3], srcB);
        P1.u[0] = hi ? a1 : a0;  P1.u[1] = hi ? b1 : b0;
        P1.u[2] = hi ? c1 : c0;  P1.u[3] = hi ? d1 : d0;
      }
      const s16x8 pf0 = P0.v, pf1 = P1.v;
      // --- l-sum via ones-MFMA (same quantized P as PV) ---
      f32x4 ls = {};
      ls = __builtin_amdgcn_mfma_f32_16x16x32_bf16(ones, pf0, ls, 0,0,0);
      ls = __builtin_amdgcn_mfma_f32_16x16x32_bf16(ones, pf1, ls, 0,0,0);
      l_q = l_q*sc + ls[0];
      if (__any(sc != 1.0f)){
        #pragma unroll
        for (int dt=0;dt<8;++dt)
          #pragma unroll
          for (int r=0;r<4;++r) accO[dt][r] *= sc;
      }
      // --- PV: O^T += V^T @ P^T (V fragments from registers) ---
      __builtin_amdgcn_s_setprio(1);
      #pragma unroll
      for (int dt=0;dt<8;++dt){
        accO[dt] = __builtin_amdgcn_mfma_f32_16x16x32_bf16(vfr[2*dt],   pf0, accO[dt], 0,0,0);
        accO[dt] = __builtin_amdgcn_mfma_f32_16x16x32_bf16(vfr[2*dt+1], pf1, accO[dt], 0,0,0);
      }
      __builtin_amdgcn_s_setprio(0);
      __syncthreads();          // staged t+1 visible; buffers swappable
      cur ^= 1;
    }
    // --- epilogue: transpose via LDS (aliases dead K staging), store ---
    const float linv = 1.0f / l_q;
    #pragma unroll
    for (int dt=0;dt<8;++dt)
      #pragma unroll
      for (int r=0;r<4;++r)
        Ol[w][lr][dt*16 + 4*g + r] = f2b(accO[dt][r] * linv);
    __syncthreads();
    #pragma unroll
    for (int p=0;p<4;++p){
      const int ql = p*4 + g;
      s16x8 ov = *(const s16x8*)(&Ol[w][ql][0] + lr*8);
      *(s16x8*)(Ob + (size_t)(q0+ql)*D_ + h*DK_ + lr*8) = ov;
    }
    __syncthreads();            // Ol reads done before next phase's STAGE_K
  }
  #undef STAGE_K
}

// ---------------------------------------------------------------------------
extern "C" void kernel_launch(void* const* d_in, const int* in_sizes, int n_in,
                              void* d_out, int out_size, void* d_ws, size_t ws_size,
                              hipStream_t stream)
{
  const void* q   = d_in[0];
  const void* k   = d_in[1];
  const void* v   = d_in[2];
  const void* wq  = d_in[3];  const void* bq = d_in[4];
  const void* laq = d_in[5];  const void* lbq= d_in[6];
  const void* wk  = d_in[7];  const void* bk = d_in[8];
  const void* lak = d_in[9];  const void* lbk= d_in[10];
  const void* wv  = d_in[11]; const void* bv = d_in[12];
  const void* lav = d_in[13]; const void* lbv= d_in[14];
  const void* wo  = d_in[15]; const void* bo = d_in[16];
  const void* lao = d_in[17]; const void* lbo= d_in[18];

  char* ws = (char*)d_ws;
  int* flag = (int*)ws;
  char* base = ws + 256;
  const size_t MB = 1u<<20;
  u16* W   = (u16*)(base);            //  8 MiB, reused for each effW^T
  u16* Qb  = (u16*)(base +  8*MB);    // 16 MiB
  u16* Kb  = (u16*)(base + 24*MB);    // 16 MiB
  u16* Vb  = (u16*)(base + 40*MB);    // 16 MiB
  u16* VTb = (u16*)(base + 56*MB);    // 16 MiB  -> total 72 MiB + 256 B
  u16* Ob  = Vb;                      // V dead after transpose

  dim3 blk(256);
  dim3 gW(D_/64, D_/64);
  dim3 gG(D_/128, MROWS/128);
  detect32<<<1, blk, 0, stream>>>((const unsigned*)q, flag);
  prep_wt<<<gW, blk, 0, stream>>>(wq, laq, lbq, W, flag);
  gemm_bt<<<gG, blk, 0, stream>>>(q, W, bq, Qb, flag, 1, 0);
  prep_wt<<<gW, blk, 0, stream>>>(wk, lak, lbk, W, flag);
  gemm_bt<<<gG, blk, 0, stream>>>(k, W, bk, Kb, flag, 1, 0);
  prep_wt<<<gW, blk, 0, stream>>>(wv, lav, lbv, W, flag);
  gemm_bt<<<gG, blk, 0, stream>>>(v, W, bv, Vb, flag, 1, 0);
  transpose_v<<<dim3(S_/64, D_/64, B_), blk, 0, stream>>>(Vb, VTb);
  attn<<<dim3(S_/128, H_, B_), blk, 0, stream>>>(Qb, Kb, VTb, Ob);
  prep_wt<<<gW, blk, 0, stream>>>(wo, lao, lbo, W, flag);
  gemm_bt<<<gG, blk, 0, stream>>>(Ob, W, bo, d_out, flag, 0, 1);
}

// Round 14
// 384.465 us; speedup vs baseline: 1.1408x; 1.1408x over previous
//
#include <hip/hip_runtime.h>

// LoRA multi-head attention forward, B=2 S=2048 D=2048 H=16 dk=128 rank=8.
// Device dtype auto-detected (bf16 vs fp32) -> flag in ws; internal compute bf16.
// Pipeline: detect -> [prep effW^T -> GEMM] x3 (Q,K,V) -> V transpose ->
// causal flash attention -> prep effWo^T -> output GEMM.
// R14: attn = R13's PAIRED blocks (q-tiles x and 31-x, 512 blocks == resident
// slots) + R12's Vs LDS staging restored (V-direct doubled FETCH, reverted).
// gemm_bt gains T1 chunked XCD swizzle (512%8==0, bijective).

#define B_   2
#define S_   2048
#define D_   2048
#define H_   16
#define DK_  128
#define MROWS (B_*S_)            // 4096
#define SCALE_ 0.08838834764831845f   // 1/sqrt(128)

using f32x4 = __attribute__((ext_vector_type(4))) float;
using s16x8 = __attribute__((ext_vector_type(8))) short;
typedef unsigned short u16;
typedef unsigned int u32;

__device__ __forceinline__ float b2f(u16 u){ union{unsigned u32v; float f;} x; x.u32v=((unsigned)u)<<16; return x.f; }
__device__ __forceinline__ u16 f2b(float f){ union{float f; unsigned u;} x; x.f=f; unsigned r=x.u+0x7fffu+((x.u>>16)&1u); return (u16)(r>>16); }
__device__ __forceinline__ u32 pk2(float lo, float hi){
  return ((u32)f2b(hi) << 16) | (u32)f2b(lo);
}

__device__ __forceinline__ void glds16(const void* g, void* l){
  __builtin_amdgcn_global_load_lds((const __attribute__((address_space(1))) unsigned int*)g,
                                   (__attribute__((address_space(3))) unsigned int*)l, 16, 0, 0);
}

// ---------------------------------------------------------------------------
__global__ void detect32(const unsigned* __restrict__ q, int* __restrict__ flag)
{
  __shared__ int s[4];
  int c = 0;
  for (int i = threadIdx.x; i < 4096; i += 256){
    unsigned u = q[i];
    unsigned e0 = (u >> 7) & 0xFFu;
    if (e0 >= 0x90u) ++c;
  }
  #pragma unroll
  for (int off = 32; off; off >>= 1) c += __shfl_down(c, off);
  if ((threadIdx.x & 63) == 0) s[threadIdx.x >> 6] = c;
  __syncthreads();
  if (threadIdx.x == 0) *flag = ((s[0]+s[1]+s[2]+s[3]) > 64) ? 1 : 0;
}

// ---------------------------------------------------------------------------
// effWT[n][k] = w[k][n] + sum_r la[k][r]*lb[r][n]
__global__ __launch_bounds__(256) void prep_wt(const void* __restrict__ w_, const void* __restrict__ la_,
                                               const void* __restrict__ lb_, u16* __restrict__ wt,
                                               const int* __restrict__ flagp)
{
  const int f32i = *flagp;
  __shared__ float tile[64][65];
  const int tid = threadIdx.x;
  const int k0 = blockIdx.x*64, n0 = blockIdx.y*64;
  const int c  = tid & 63;
  const int r0 = (tid >> 6) * 16;
  float lbv[8];
  if (f32i){
    const float* lb = (const float*)lb_;
    #pragma unroll
    for (int r=0;r<8;++r) lbv[r] = lb[(size_t)r*D_ + n0 + c];
  } else {
    const u16* lb = (const u16*)lb_;
    #pragma unroll
    for (int r=0;r<8;++r) lbv[r] = b2f(lb[(size_t)r*D_ + n0 + c]);
  }
  #pragma unroll
  for (int kk=0;kk<16;++kk){
    const int k = k0 + r0 + kk;
    float val;
    if (f32i){
      const float* w32 = (const float*)w_;  const float* la = (const float*)la_;
      val = w32[(size_t)k*D_ + n0 + c];
      f32x4 a0 = *(const f32x4*)(la + k*8);
      f32x4 a1 = *(const f32x4*)(la + k*8 + 4);
      #pragma unroll
      for (int r=0;r<4;++r) val += a0[r]*lbv[r];
      #pragma unroll
      for (int r=0;r<4;++r) val += a1[r]*lbv[4+r];
    } else {
      const u16* w16 = (const u16*)w_;  const u16* la = (const u16*)la_;
      val = b2f(w16[(size_t)k*D_ + n0 + c]);
      s16x8 av = *(const s16x8*)(la + k*8);
      #pragma unroll
      for (int r=0;r<8;++r) val += b2f((u16)av[r])*lbv[r];
    }
    tile[r0+kk][c] = val;
  }
  __syncthreads();
  #pragma unroll
  for (int nn=0;nn<16;++nn){
    const int nr = r0 + nn;
    wt[(size_t)(n0+nr)*D_ + k0 + c] = f2b(tile[c][nr]);
  }
}

// ---------------------------------------------------------------------------
__global__ __launch_bounds__(256) void transpose_v(const u16* __restrict__ V, u16* __restrict__ VT)
{
  __shared__ u16 tile[64][66];
  const int bz = blockIdx.z;
  const int s0 = blockIdx.x*64, d0 = blockIdx.y*64;
  const int tid = threadIdx.x;
  const u16* Vb = V + (size_t)bz*S_*D_;
  u16* VTb = VT + (size_t)bz*D_*S_;
  const int c = tid & 63, r0 = (tid>>6)*16;
  #pragma unroll
  for (int i=0;i<16;++i) tile[r0+i][c] = Vb[(size_t)(s0+r0+i)*D_ + d0 + c];
  __syncthreads();
  #pragma unroll
  for (int i=0;i<16;++i) VTb[(size_t)(d0+r0+i)*S_ + s0 + c] = tile[c][r0+i];
}

// ---------------------------------------------------------------------------
// C[m][n] = sum_k A[m][k]*BT[n][k] + bias[n].  M=4096, N=K=2048.
// 128x128 tile, BK=64, double-buffered prefetch, one barrier/iter.
// T1 chunked XCD swizzle: each XCD gets 64 consecutive flat block ids
// (4 A-panels) -> A-panel reuse inside one per-XCD L2.
// Swizzle invariant: LDS[row][c] = global[row][c ^ ((row&7)<<3)] (u16 units).
__global__ __launch_bounds__(256) void gemm_bt(const void* __restrict__ A_, const u16* __restrict__ BT,
                                               const void* __restrict__ bias_, void* __restrict__ C_,
                                               const int* __restrict__ flagp, int aF, int oF)
{
  constexpr int N = D_, K = D_;
  constexpr int NT = K/64;
  const int f = *flagp;
  const bool a32 = (aF != 0) && (f != 0);
  const bool o32 = (oF != 0) && (f != 0);
  __shared__ u16 As[2][128*64];      // 32 KB
  __shared__ u16 Bs[2][128*64];      // 32 KB
  const int tid = threadIdx.x;
  const int w = tid>>6, lane = tid&63, g = lane>>4, lr = lane&15;
  const int wm = w>>1, wn = w&1;
  // T1 XCD swizzle (requires nwg % 8 == 0; here 16*32=512)
  const unsigned flat = blockIdx.y*gridDim.x + blockIdx.x;
  const unsigned cpx  = (gridDim.x*gridDim.y) >> 3;        // 64
  const unsigned swz  = (flat & 7)*cpx + (flat >> 3);
  const int m0 = (int)(swz / gridDim.x) * 128;
  const int n0 = (int)(swz % gridDim.x) * 128;
  const int srow = lane>>3;                        // 0..7
  const int lcol = (lane&7)*8;                     // linear col, u16 units
  const int scol = lcol ^ (srow<<3);               // swizzled col
  const int rsw  = (lr&7)<<3;                      // read-side swizzle (u16)

  const float* Af = (const float*)A_;
  const u16*   Ab = (const u16*)A_;

  #define STAGE_B16(buf, k0_) do{ _Pragma("unroll")                                 \
    for (int jj=0;jj<4;++jj){ const int rb = w*32 + jj*8;                           \
      glds16(BT + (size_t)(n0+rb+srow)*K + (k0_) + scol, (void*)(&Bs[buf][0] + rb*64)); } }while(0)
  #define STAGE_A16(buf, k0_) do{ _Pragma("unroll")                                 \
    for (int jj=0;jj<4;++jj){ const int rb = w*32 + jj*8;                           \
      glds16(Ab + (size_t)(m0+rb+srow)*K + (k0_) + scol, (void*)(&As[buf][0] + rb*64)); } }while(0)
  #define LOAD_A32(k0_) do{ _Pragma("unroll")                                       \
    for (int jj=0;jj<4;++jj){                                                       \
      const float* src = Af + (size_t)(m0 + w*32 + jj*8 + srow)*K + (k0_) + lcol;   \
      ax0[jj] = *(const f32x4*)src; ax1[jj] = *(const f32x4*)(src + 4); } }while(0)
  #define WRITE_A32(buf) do{ _Pragma("unroll")                                      \
    for (int jj=0;jj<4;++jj){ const int rb = w*32 + jj*8; s16x8 pk;                 \
      _Pragma("unroll")                                                             \
      for (int i=0;i<4;++i){ pk[i]=(short)f2b(ax0[jj][i]); pk[4+i]=(short)f2b(ax1[jj][i]); } \
      *(s16x8*)(&As[buf][0] + (rb+srow)*64 + scol) = pk; } }while(0)

  f32x4 ax0[4], ax1[4];
  f32x4 acc[4][4] = {};

  if (a32){ LOAD_A32(0); WRITE_A32(0); } else { STAGE_A16(0, 0); }
  STAGE_B16(0, 0);
  __syncthreads();

  int cur = 0;
  for (int t=0; t<NT; ++t){
    const bool haveNext = (t+1 < NT);
    if (haveNext){
      if (a32) LOAD_A32((t+1)*64);              // issue early; write after compute
      else     STAGE_A16(cur^1, (t+1)*64);
      STAGE_B16(cur^1, (t+1)*64);
    }
    #pragma unroll
    for (int kk=0;kk<2;++kk){
      s16x8 af[4], bfr[4];
      #pragma unroll
      for (int i=0;i<4;++i) af[i]  = *(const s16x8*)(&As[cur][0] + (wm*64+i*16+lr)*64 + ((kk*32 + g*8) ^ rsw));
      #pragma unroll
      for (int i=0;i<4;++i) bfr[i] = *(const s16x8*)(&Bs[cur][0] + (wn*64+i*16+lr)*64 + ((kk*32 + g*8) ^ rsw));
      #pragma unroll
      for (int mi=0;mi<4;++mi)
        #pragma unroll
        for (int ni=0;ni<4;++ni)
          acc[mi][ni] = __builtin_amdgcn_mfma_f32_16x16x32_bf16(af[mi], bfr[ni], acc[mi][ni], 0,0,0);
    }
    if (haveNext && a32) WRITE_A32(cur^1);      // vmcnt wait lands after MFMAs
    __syncthreads();
    cur ^= 1;
  }
  #pragma unroll
  for (int ni=0;ni<4;++ni){
    const int n = n0 + wn*64 + ni*16 + lr;
    const float bv = f ? ((const float*)bias_)[n] : b2f(((const u16*)bias_)[n]);
    #pragma unroll
    for (int mi=0;mi<4;++mi){
      const int m = m0 + wm*64 + mi*16 + 4*g;
      #pragma unroll
      for (int r=0;r<4;++r){
        const float val = acc[mi][ni][r] + bv;
        if (o32) ((float*)C_)[(size_t)(m+r)*N + n] = val;
        else     ((u16*)C_)[(size_t)(m+r)*N + n] = f2b(val);
      }
    }
  }
  #undef STAGE_B16
  #undef STAGE_A16
  #undef LOAD_A32
  #undef WRITE_A32
}

// ---------------------------------------------------------------------------
// Causal flash attention.  grid (S/128, H, B), block 256 (4 waves x 16 q-rows).
// PAIRED blocks: block x handles q-tiles x and 31-x -> constant 33 tile-units;
// 512 blocks == 512 resident slots (2 blocks/CU) -> no tail.  K and V staged
// in LDS (dbuf, XOR swizzle, 1 barrier/tile).  Swapped QK^T, lane-local
// softmax (q=lr), f2b pack + 16-shfl gather, ones-MFMA l-sum, defer-max THR=8.
__global__ __launch_bounds__(256) void attn(const u16* __restrict__ Q, const u16* __restrict__ K,
                                            const u16* __restrict__ VT, u16* __restrict__ O)
{
  __shared__ u16  Ks[2][64*128];     // 32 KB, rows kv (256B), swizzled
  __shared__ u16  Vs[2][128*64];     // 32 KB, rows d (128B), swizzled
  u16 (*Ol)[16][136] = (u16(*)[16][136])(&Ks[0][0]);   // epilogue alias, dead staging

  const int tid = threadIdx.x;
  const int w = tid>>6, lane = tid&63, g = lane>>4, lr = lane&15;
  const int h = blockIdx.y, bz = blockIdx.z;
  const u16* Qb  = Q  + (size_t)bz*S_*D_;
  const u16* Kb  = K  + (size_t)bz*S_*D_;
  const u16* VTb = VT + (size_t)bz*D_*S_;
  u16* Ob = O + (size_t)bz*S_*D_;
  const int sw = (lr&7)<<4;                 // read-side swizzle (bytes)
  const int krow_l = lane>>4, kcol_l = (lane&15)*16;   // K staging lane map
  const int vrow_l = lane>>3, vcol_l = (lane&7)*16;    // V staging lane map

  s16x8 ones;
  #pragma unroll
  for (int i=0;i<8;++i) ones[i] = (short)0x3F80;       // bf16 1.0

  #define STAGE_K(buf, t_) do{ const int kv0s = (t_)*64;                            \
    _Pragma("unroll")                                                               \
    for (int jj=0;jj<4;++jj){ const int j = w*4 + jj; const int r = j*4 + krow_l;   \
      const int cb = kcol_l ^ ((r&7)<<4);                                           \
      glds16(Kb + (size_t)(kv0s + r)*D_ + h*DK_ + (cb>>1), (void*)(&Ks[buf][0] + j*512)); } }while(0)
  #define STAGE_V(buf, t_) do{ const int kv0s = (t_)*64;                            \
    _Pragma("unroll")                                                               \
    for (int jj=0;jj<4;++jj){ const int j = w*4 + jj; const int r = j*8 + vrow_l;   \
      const int cb = vcol_l ^ ((r&7)<<4);                                           \
      glds16(VTb + (size_t)(h*DK_ + r)*S_ + kv0s + (cb>>1), (void*)(&Vs[buf][0] + j*512)); } }while(0)

  for (int qq=0; qq<2; ++qq){
    const int qt = qq ? (int)(S_/64 - 1 - blockIdx.x) : (int)blockIdx.x;
    const int q0 = qt*64 + w*16;
    const int nt = qt + 1;

    // Q fragments, pre-scaled by 1/sqrt(dk)
    s16x8 qf[4];
    #pragma unroll
    for (int dc=0;dc<4;++dc){
      s16x8 t = *(const s16x8*)(Qb + (size_t)(q0+lr)*D_ + h*DK_ + dc*32 + g*8);
      #pragma unroll
      for (int i=0;i<8;++i) t[i] = (short)f2b(b2f((u16)t[i]) * SCALE_);
      qf[dc] = t;
    }
    float m_  = -1e30f;              // running max for q-row lr (lane-local)
    float l_q = 0.f;                 // row-sum for q-row lr (lane-local)
    f32x4 accO[8] = {};              // O^T[d=dt*16+4g+r][q=lr], fp32

    STAGE_K(0, 0); STAGE_V(0, 0);
    __syncthreads();
    int cur = 0;
    for (int t=0;t<nt;++t){
      const int kv0 = t*64;
      const bool lastT = (t == nt-1);
      if (!lastT){ STAGE_K(cur^1, t+1); STAGE_V(cur^1, t+1); }
      // --- QK^T (swapped): sacc[kt][r] = S[q=lr][key=kt*16+4g+r] ---
      const u16* Ksc = &Ks[cur][0];
      f32x4 sacc[4] = {};
      __builtin_amdgcn_s_setprio(1);
      #pragma unroll
      for (int dc=0;dc<4;++dc){
        const int cb = (dc*64 + g*16) ^ sw;
        #pragma unroll
        for (int kt=0;kt<4;++kt){
          s16x8 kf = *(const s16x8*)(Ksc + (kt*16+lr)*128 + (cb>>1));
          sacc[kt] = __builtin_amdgcn_mfma_f32_16x16x32_bf16(kf, qf[dc], sacc[kt], 0,0,0);
        }
      }
      __builtin_amdgcn_s_setprio(0);
      if (lastT){
        #pragma unroll
        for (int kt=0;kt<4;++kt)
          #pragma unroll
          for (int r=0;r<4;++r)
            if (kv0 + kt*16 + 4*g + r > q0 + lr) sacc[kt][r] = -1e30f;
      }
      // --- lane-local online softmax (q=lr), defer-max THR=8 ---
      float tm = sacc[0][0];
      #pragma unroll
      for (int kt=0;kt<4;++kt)
        #pragma unroll
        for (int r=0;r<4;++r) tm = fmaxf(tm, sacc[kt][r]);
      tm = fmaxf(tm, __shfl_xor(tm, 16));
      tm = fmaxf(tm, __shfl_xor(tm, 32));
      const float mn = (tm <= m_ + 8.f) ? m_ : tm;   // defer small growth
      const float sc = __expf(m_ - mn);              // ==1 when deferred
      m_ = mn;
      #pragma unroll
      for (int kt=0;kt<4;++kt)
        #pragma unroll
        for (int r=0;r<4;++r) sacc[kt][r] = __expf(sacc[kt][r] - mn);
      // --- pack P to bf16 pairs (f2b) and gather B-operand fragments ---
      u32 pa[4], pb[4];
      #pragma unroll
      for (int kt=0;kt<4;++kt){
        pa[kt] = pk2(sacc[kt][0], sacc[kt][1]);
        pb[kt] = pk2(sacc[kt][2], sacc[kt][3]);
      }
      const int srcA = lr + 32*(g&1);
      const int srcB = srcA + 16;
      const bool hi = (g >= 2);
      union { s16x8 v; u32 u[4]; } P0, P1;
      {
        u32 a0 = (u32)__shfl((int)pa[0], srcA), a1 = (u32)__shfl((int)pa[1], srcA);
        u32 b0 = (u32)__shfl((int)pb[0], srcA), b1 = (u32)__shfl((int)pb[1], srcA);
        u32 c0 = (u32)__shfl((int)pa[0], srcB), c1 = (u32)__shfl((int)pa[1], srcB);
        u32 d0 = (u32)__shfl((int)pb[0], srcB), d1 = (u32)__shfl((int)pb[1], srcB);
        P0.u[0] = hi ? a1 : a0;  P0.u[1] = hi ? b1 : b0;
        P0.u[2] = hi ? c1 : c0;  P0.u[3] = hi ? d1 : d0;
      }
      {
        u32 a0 = (u32)__shfl((int)pa[2], srcA), a1 = (u32)__shfl((int)pa[3], srcA);
        u32 b0 = (u32)__shfl((int)pb[2], srcA), b1 = (u32)__shfl((int)pb[3], srcA);
        u32 c0 = (u32)__shfl((int)pa[2], srcB), c1 = (u32)__shfl((int)pa[3], srcB);
        u32 d0 = (u32)__shfl((int)pb[2], srcB), d1 = (u32)__shfl((int)pb[3], srcB);
        P1.u[0] = hi ? a1 : a0;  P1.u[1] = hi ? b1 : b0;
        P1.u[2] = hi ? c1 : c0;  P1.u[3] = hi ? d1 : d0;
      }
      const s16x8 pf0 = P0.v, pf1 = P1.v;
      // --- l-sum via ones-MFMA (same quantized P as PV) ---
      f32x4 ls = {};
      ls = __builtin_amdgcn_mfma_f32_16x16x32_bf16(ones, pf0, ls, 0,0,0);
      ls = __builtin_amdgcn_mfma_f32_16x16x32_bf16(ones, pf1, ls, 0,0,0);
      l_q = l_q*sc + ls[0];
      if (__any(sc != 1.0f)){
        #pragma unroll
        for (int dt=0;dt<8;++dt)
          #pragma unroll
          for (int r=0;r<4;++r) accO[dt][r] *= sc;
      }
      // --- PV: O^T += V^T @ P^T (V from LDS) ---
      const u16* Vsc = &Vs[cur][0];
      const int cb0 = (g*16) ^ sw;
      const int cb1 = (64 + g*16) ^ sw;
      __builtin_amdgcn_s_setprio(1);
      #pragma unroll
      for (int dt=0;dt<8;++dt){
        s16x8 vf0 = *(const s16x8*)(Vsc + (dt*16+lr)*64 + (cb0>>1));
        accO[dt] = __builtin_amdgcn_mfma_f32_16x16x32_bf16(vf0, pf0, accO[dt], 0,0,0);
        s16x8 vf1 = *(const s16x8*)(Vsc + (dt*16+lr)*64 + (cb1>>1));
        accO[dt] = __builtin_amdgcn_mfma_f32_16x16x32_bf16(vf1, pf1, accO[dt], 0,0,0);
      }
      __builtin_amdgcn_s_setprio(0);
      __syncthreads();          // staged t+1 visible; buffers swappable
      cur ^= 1;
    }
    // --- epilogue: transpose via LDS (aliases dead K staging), store ---
    const float linv = 1.0f / l_q;
    #pragma unroll
    for (int dt=0;dt<8;++dt)
      #pragma unroll
      for (int r=0;r<4;++r)
        Ol[w][lr][dt*16 + 4*g + r] = f2b(accO[dt][r] * linv);
    __syncthreads();
    #pragma unroll
    for (int p=0;p<4;++p){
      const int ql = p*4 + g;
      s16x8 ov = *(const s16x8*)(&Ol[w][ql][0] + lr*8);
      *(s16x8*)(Ob + (size_t)(q0+ql)*D_ + h*DK_ + lr*8) = ov;
    }
    __syncthreads();            // Ol reads done before next phase's STAGE_K
  }
  #undef STAGE_K
  #undef STAGE_V
}

// ---------------------------------------------------------------------------
extern "C" void kernel_launch(void* const* d_in, const int* in_sizes, int n_in,
                              void* d_out, int out_size, void* d_ws, size_t ws_size,
                              hipStream_t stream)
{
  const void* q   = d_in[0];
  const void* k   = d_in[1];
  const void* v   = d_in[2];
  const void* wq  = d_in[3];  const void* bq = d_in[4];
  const void* laq = d_in[5];  const void* lbq= d_in[6];
  const void* wk  = d_in[7];  const void* bk = d_in[8];
  const void* lak = d_in[9];  const void* lbk= d_in[10];
  const void* wv  = d_in[11]; const void* bv = d_in[12];
  const void* lav = d_in[13]; const void* lbv= d_in[14];
  const void* wo  = d_in[15]; const void* bo = d_in[16];
  const void* lao = d_in[17]; const void* lbo= d_in[18];

  char* ws = (char*)d_ws;
  int* flag = (int*)ws;
  char* base = ws + 256;
  const size_t MB = 1u<<20;
  u16* W   = (u16*)(base);            //  8 MiB, reused for each effW^T
  u16* Qb  = (u16*)(base +  8*MB);    // 16 MiB
  u16* Kb  = (u16*)(base + 24*MB);    // 16 MiB
  u16* Vb  = (u16*)(base + 40*MB);    // 16 MiB
  u16* VTb = (u16*)(base + 56*MB);    // 16 MiB  -> total 72 MiB + 256 B
  u16* Ob  = Vb;                      // V dead after transpose

  dim3 blk(256);
  dim3 gW(D_/64, D_/64);
  dim3 gG(D_/128, MROWS/128);
  detect32<<<1, blk, 0, stream>>>((const unsigned*)q, flag);
  prep_wt<<<gW, blk, 0, stream>>>(wq, laq, lbq, W, flag);
  gemm_bt<<<gG, blk, 0, stream>>>(q, W, bq, Qb, flag, 1, 0);
  prep_wt<<<gW, blk, 0, stream>>>(wk, lak, lbk, W, flag);
  gemm_bt<<<gG, blk, 0, stream>>>(k, W, bk, Kb, flag, 1, 0);
  prep_wt<<<gW, blk, 0, stream>>>(wv, lav, lbv, W, flag);
  gemm_bt<<<gG, blk, 0, stream>>>(v, W, bv, Vb, flag, 1, 0);
  transpose_v<<<dim3(S_/64, D_/64, B_), blk, 0, stream>>>(Vb, VTb);
  attn<<<dim3(S_/128, H_, B_), blk, 0, stream>>>(Qb, Kb, VTb, Ob);
  prep_wt<<<gW, blk, 0, stream>>>(wo, lao, lbo, W, flag);
  gemm_bt<<<gG, blk, 0, stream>>>(Ob, W, bo, d_out, flag, 0, 1);
}

// Round 16
// 379.514 us; speedup vs baseline: 1.1557x; 1.0130x over previous
//
#include <hip/hip_runtime.h>

// LoRA multi-head attention forward, B=2 S=2048 D=2048 H=16 dk=128 rank=8.
// Device dtype auto-detected (bf16 vs fp32) -> flag in ws; internal compute bf16.
// Pipeline: detect -> [prep effW^T -> GEMM] x3 (Q,K,V) -> V transpose ->
// causal flash attention -> prep effWo^T -> output GEMM.
// R16: determinism hardening. attn = R14 structure (paired blocks, LDS KV,
// no XCD remap) + sched_barrier(0) after each loop __syncthreads (pins
// prefetch below the barrier; suspected hoist race) + defer-max removed
// (P<=1, 4x absmax margin).  GEMM identical to R14 (dbuf BK=64 + XCD swizzle).

#define B_   2
#define S_   2048
#define D_   2048
#define H_   16
#define DK_  128
#define MROWS (B_*S_)            // 4096
#define SCALE_ 0.08838834764831845f   // 1/sqrt(128)

using f32x4 = __attribute__((ext_vector_type(4))) float;
using s16x8 = __attribute__((ext_vector_type(8))) short;
typedef unsigned short u16;
typedef unsigned int u32;

__device__ __forceinline__ float b2f(u16 u){ union{unsigned u32v; float f;} x; x.u32v=((unsigned)u)<<16; return x.f; }
__device__ __forceinline__ u16 f2b(float f){ union{float f; unsigned u;} x; x.f=f; unsigned r=x.u+0x7fffu+((x.u>>16)&1u); return (u16)(r>>16); }
__device__ __forceinline__ u32 pk2(float lo, float hi){
  return ((u32)f2b(hi) << 16) | (u32)f2b(lo);
}

__device__ __forceinline__ void glds16(const void* g, void* l){
  __builtin_amdgcn_global_load_lds((const __attribute__((address_space(1))) unsigned int*)g,
                                   (__attribute__((address_space(3))) unsigned int*)l, 16, 0, 0);
}

// ---------------------------------------------------------------------------
__global__ void detect32(const unsigned* __restrict__ q, int* __restrict__ flag)
{
  __shared__ int s[4];
  int c = 0;
  for (int i = threadIdx.x; i < 4096; i += 256){
    unsigned u = q[i];
    unsigned e0 = (u >> 7) & 0xFFu;
    if (e0 >= 0x90u) ++c;
  }
  #pragma unroll
  for (int off = 32; off; off >>= 1) c += __shfl_down(c, off);
  if ((threadIdx.x & 63) == 0) s[threadIdx.x >> 6] = c;
  __syncthreads();
  if (threadIdx.x == 0) *flag = ((s[0]+s[1]+s[2]+s[3]) > 64) ? 1 : 0;
}

// ---------------------------------------------------------------------------
// effWT[n][k] = w[k][n] + sum_r la[k][r]*lb[r][n]
__global__ __launch_bounds__(256) void prep_wt(const void* __restrict__ w_, const void* __restrict__ la_,
                                               const void* __restrict__ lb_, u16* __restrict__ wt,
                                               const int* __restrict__ flagp)
{
  const int f32i = *flagp;
  __shared__ float tile[64][65];
  const int tid = threadIdx.x;
  const int k0 = blockIdx.x*64, n0 = blockIdx.y*64;
  const int c  = tid & 63;
  const int r0 = (tid >> 6) * 16;
  float lbv[8];
  if (f32i){
    const float* lb = (const float*)lb_;
    #pragma unroll
    for (int r=0;r<8;++r) lbv[r] = lb[(size_t)r*D_ + n0 + c];
  } else {
    const u16* lb = (const u16*)lb_;
    #pragma unroll
    for (int r=0;r<8;++r) lbv[r] = b2f(lb[(size_t)r*D_ + n0 + c]);
  }
  #pragma unroll
  for (int kk=0;kk<16;++kk){
    const int k = k0 + r0 + kk;
    float val;
    if (f32i){
      const float* w32 = (const float*)w_;  const float* la = (const float*)la_;
      val = w32[(size_t)k*D_ + n0 + c];
      f32x4 a0 = *(const f32x4*)(la + k*8);
      f32x4 a1 = *(const f32x4*)(la + k*8 + 4);
      #pragma unroll
      for (int r=0;r<4;++r) val += a0[r]*lbv[r];
      #pragma unroll
      for (int r=0;r<4;++r) val += a1[r]*lbv[4+r];
    } else {
      const u16* w16 = (const u16*)w_;  const u16* la = (const u16*)la_;
      val = b2f(w16[(size_t)k*D_ + n0 + c]);
      s16x8 av = *(const s16x8*)(la + k*8);
      #pragma unroll
      for (int r=0;r<8;++r) val += b2f((u16)av[r])*lbv[r];
    }
    tile[r0+kk][c] = val;
  }
  __syncthreads();
  #pragma unroll
  for (int nn=0;nn<16;++nn){
    const int nr = r0 + nn;
    wt[(size_t)(n0+nr)*D_ + k0 + c] = f2b(tile[c][nr]);
  }
}

// ---------------------------------------------------------------------------
__global__ __launch_bounds__(256) void transpose_v(const u16* __restrict__ V, u16* __restrict__ VT)
{
  __shared__ u16 tile[64][66];
  const int bz = blockIdx.z;
  const int s0 = blockIdx.x*64, d0 = blockIdx.y*64;
  const int tid = threadIdx.x;
  const u16* Vb = V + (size_t)bz*S_*D_;
  u16* VTb = VT + (size_t)bz*D_*S_;
  const int c = tid & 63, r0 = (tid>>6)*16;
  #pragma unroll
  for (int i=0;i<16;++i) tile[r0+i][c] = Vb[(size_t)(s0+r0+i)*D_ + d0 + c];
  __syncthreads();
  #pragma unroll
  for (int i=0;i<16;++i) VTb[(size_t)(d0+r0+i)*S_ + s0 + c] = tile[c][r0+i];
}

// ---------------------------------------------------------------------------
// C[m][n] = sum_k A[m][k]*BT[n][k] + bias[n].  M=4096, N=K=2048.
// 128x128 tile, BK=64, double-buffered prefetch, one barrier/iter.
// T1 chunked XCD swizzle (512%8==0, bijective).
// Swizzle invariant: LDS[row][c] = global[row][c ^ ((row&7)<<3)] (u16 units).
__global__ __launch_bounds__(256) void gemm_bt(const void* __restrict__ A_, const u16* __restrict__ BT,
                                               const void* __restrict__ bias_, void* __restrict__ C_,
                                               const int* __restrict__ flagp, int aF, int oF)
{
  constexpr int N = D_, K = D_;
  constexpr int NT = K/64;
  const int f = *flagp;
  const bool a32 = (aF != 0) && (f != 0);
  const bool o32 = (oF != 0) && (f != 0);
  __shared__ u16 As[2][128*64];      // 32 KB
  __shared__ u16 Bs[2][128*64];      // 32 KB
  const int tid = threadIdx.x;
  const int w = tid>>6, lane = tid&63, g = lane>>4, lr = lane&15;
  const int wm = w>>1, wn = w&1;
  // T1 XCD swizzle (requires nwg % 8 == 0; here 16*32=512)
  const unsigned flat = blockIdx.y*gridDim.x + blockIdx.x;
  const unsigned cpx  = (gridDim.x*gridDim.y) >> 3;        // 64
  const unsigned swz  = (flat & 7)*cpx + (flat >> 3);
  const int m0 = (int)(swz / gridDim.x) * 128;
  const int n0 = (int)(swz % gridDim.x) * 128;
  const int srow = lane>>3;                        // 0..7
  const int lcol = (lane&7)*8;                     // linear col, u16 units
  const int scol = lcol ^ (srow<<3);               // swizzled col
  const int rsw  = (lr&7)<<3;                      // read-side swizzle (u16)

  const float* Af = (const float*)A_;
  const u16*   Ab = (const u16*)A_;

  #define STAGE_B16(buf, k0_) do{ _Pragma("unroll")                                 \
    for (int jj=0;jj<4;++jj){ const int rb = w*32 + jj*8;                           \
      glds16(BT + (size_t)(n0+rb+srow)*K + (k0_) + scol, (void*)(&Bs[buf][0] + rb*64)); } }while(0)
  #define STAGE_A16(buf, k0_) do{ _Pragma("unroll")                                 \
    for (int jj=0;jj<4;++jj){ const int rb = w*32 + jj*8;                           \
      glds16(Ab + (size_t)(m0+rb+srow)*K + (k0_) + scol, (void*)(&As[buf][0] + rb*64)); } }while(0)
  #define LOAD_A32(k0_) do{ _Pragma("unroll")                                       \
    for (int jj=0;jj<4;++jj){                                                       \
      const float* src = Af + (size_t)(m0 + w*32 + jj*8 + srow)*K + (k0_) + lcol;   \
      ax0[jj] = *(const f32x4*)src; ax1[jj] = *(const f32x4*)(src + 4); } }while(0)
  #define WRITE_A32(buf) do{ _Pragma("unroll")                                      \
    for (int jj=0;jj<4;++jj){ const int rb = w*32 + jj*8; s16x8 pk;                 \
      _Pragma("unroll")                                                             \
      for (int i=0;i<4;++i){ pk[i]=(short)f2b(ax0[jj][i]); pk[4+i]=(short)f2b(ax1[jj][i]); } \
      *(s16x8*)(&As[buf][0] + (rb+srow)*64 + scol) = pk; } }while(0)

  f32x4 ax0[4], ax1[4];
  f32x4 acc[4][4] = {};

  if (a32){ LOAD_A32(0); WRITE_A32(0); } else { STAGE_A16(0, 0); }
  STAGE_B16(0, 0);
  __syncthreads();
  __builtin_amdgcn_sched_barrier(0);

  int cur = 0;
  for (int t=0; t<NT; ++t){
    const bool haveNext = (t+1 < NT);
    if (haveNext){
      if (a32) LOAD_A32((t+1)*64);              // issue early; write after compute
      else     STAGE_A16(cur^1, (t+1)*64);
      STAGE_B16(cur^1, (t+1)*64);
    }
    #pragma unroll
    for (int kk=0;kk<2;++kk){
      s16x8 af[4], bfr[4];
      #pragma unroll
      for (int i=0;i<4;++i) af[i]  = *(const s16x8*)(&As[cur][0] + (wm*64+i*16+lr)*64 + ((kk*32 + g*8) ^ rsw));
      #pragma unroll
      for (int i=0;i<4;++i) bfr[i] = *(const s16x8*)(&Bs[cur][0] + (wn*64+i*16+lr)*64 + ((kk*32 + g*8) ^ rsw));
      #pragma unroll
      for (int mi=0;mi<4;++mi)
        #pragma unroll
        for (int ni=0;ni<4;++ni)
          acc[mi][ni] = __builtin_amdgcn_mfma_f32_16x16x32_bf16(af[mi], bfr[ni], acc[mi][ni], 0,0,0);
    }
    if (haveNext && a32) WRITE_A32(cur^1);      // vmcnt wait lands after MFMAs
    __syncthreads();
    __builtin_amdgcn_sched_barrier(0);          // pin next-iter staging below barrier
    cur ^= 1;
  }
  #pragma unroll
  for (int ni=0;ni<4;++ni){
    const int n = n0 + wn*64 + ni*16 + lr;
    const float bv = f ? ((const float*)bias_)[n] : b2f(((const u16*)bias_)[n]);
    #pragma unroll
    for (int mi=0;mi<4;++mi){
      const int m = m0 + wm*64 + mi*16 + 4*g;
      #pragma unroll
      for (int r=0;r<4;++r){
        const float val = acc[mi][ni][r] + bv;
        if (o32) ((float*)C_)[(size_t)(m+r)*N + n] = val;
        else     ((u16*)C_)[(size_t)(m+r)*N + n] = f2b(val);
      }
    }
  }
  #undef STAGE_B16
  #undef STAGE_A16
  #undef LOAD_A32
  #undef WRITE_A32
}

// ---------------------------------------------------------------------------
// Causal flash attention.  grid (S/128, H, B), block 256 (4 waves x 16 q-rows).
// PAIRED blocks: block x handles q-tiles x and 31-x -> constant 33 tile-units;
// 512 blocks == 512 resident slots (2 blocks/CU) -> no tail.  K,V staged in
// LDS (dbuf, XOR swizzle, 1 barrier/tile + sched_barrier pin).  Swapped QK^T,
// lane-local softmax (q=lr, FULL online max — defer-max removed for margin),
// f2b pack + 16-shfl gather, ones-MFMA l-sum.
__global__ __launch_bounds__(256) void attn(const u16* __restrict__ Q, const u16* __restrict__ K,
                                            const u16* __restrict__ VT, u16* __restrict__ O)
{
  __shared__ u16  Ks[2][64*128];     // 32 KB, rows kv (256B), swizzled
  __shared__ u16  Vs[2][128*64];     // 32 KB, rows d (128B), swizzled
  u16 (*Ol)[16][136] = (u16(*)[16][136])(&Ks[0][0]);   // epilogue alias, dead staging

  const int tid = threadIdx.x;
  const int w = tid>>6, lane = tid&63, g = lane>>4, lr = lane&15;
  const int h = blockIdx.y, bz = blockIdx.z;
  const u16* Qb  = Q  + (size_t)bz*S_*D_;
  const u16* Kb  = K  + (size_t)bz*S_*D_;
  const u16* VTb = VT + (size_t)bz*D_*S_;
  u16* Ob = O + (size_t)bz*S_*D_;
  const int sw = (lr&7)<<4;                 // read-side swizzle (bytes)
  const int krow_l = lane>>4, kcol_l = (lane&15)*16;   // K staging lane map
  const int vrow_l = lane>>3, vcol_l = (lane&7)*16;    // V staging lane map

  s16x8 ones;
  #pragma unroll
  for (int i=0;i<8;++i) ones[i] = (short)0x3F80;       // bf16 1.0

  #define STAGE_K(buf, t_) do{ const int kv0s = (t_)*64;                            \
    _Pragma("unroll")                                                               \
    for (int jj=0;jj<4;++jj){ const int j = w*4 + jj; const int r = j*4 + krow_l;   \
      const int cb = kcol_l ^ ((r&7)<<4);                                           \
      glds16(Kb + (size_t)(kv0s + r)*D_ + h*DK_ + (cb>>1), (void*)(&Ks[buf][0] + j*512)); } }while(0)
  #define STAGE_V(buf, t_) do{ const int kv0s = (t_)*64;                            \
    _Pragma("unroll")                                                               \
    for (int jj=0;jj<4;++jj){ const int j = w*4 + jj; const int r = j*8 + vrow_l;   \
      const int cb = vcol_l ^ ((r&7)<<4);                                           \
      glds16(VTb + (size_t)(h*DK_ + r)*S_ + kv0s + (cb>>1), (void*)(&Vs[buf][0] + j*512)); } }while(0)

  for (int qq=0; qq<2; ++qq){
    const int qt = qq ? (int)(S_/64 - 1 - blockIdx.x) : (int)blockIdx.x;
    const int q0 = qt*64 + w*16;
    const int nt = qt + 1;

    // Q fragments, pre-scaled by 1/sqrt(dk)
    s16x8 qf[4];
    #pragma unroll
    for (int dc=0;dc<4;++dc){
      s16x8 t = *(const s16x8*)(Qb + (size_t)(q0+lr)*D_ + h*DK_ + dc*32 + g*8);
      #pragma unroll
      for (int i=0;i<8;++i) t[i] = (short)f2b(b2f((u16)t[i]) * SCALE_);
      qf[dc] = t;
    }
    float m_  = -1e30f;              // running max for q-row lr (lane-local)
    float l_q = 0.f;                 // row-sum for q-row lr (lane-local)
    f32x4 accO[8] = {};              // O^T[d=dt*16+4g+r][q=lr], fp32

    STAGE_K(0, 0); STAGE_V(0, 0);
    __syncthreads();
    __builtin_amdgcn_sched_barrier(0);
    int cur = 0;
    for (int t=0;t<nt;++t){
      const int kv0 = t*64;
      const bool lastT = (t == nt-1);
      if (!lastT){ STAGE_K(cur^1, t+1); STAGE_V(cur^1, t+1); }
      // --- QK^T (swapped): sacc[kt][r] = S[q=lr][key=kt*16+4g+r] ---
      const u16* Ksc = &Ks[cur][0];
      f32x4 sacc[4] = {};
      __builtin_amdgcn_s_setprio(1);
      #pragma unroll
      for (int dc=0;dc<4;++dc){
        const int cb = (dc*64 + g*16) ^ sw;
        #pragma unroll
        for (int kt=0;kt<4;++kt){
          s16x8 kf = *(const s16x8*)(Ksc + (kt*16+lr)*128 + (cb>>1));
          sacc[kt] = __builtin_amdgcn_mfma_f32_16x16x32_bf16(kf, qf[dc], sacc[kt], 0,0,0);
        }
      }
      __builtin_amdgcn_s_setprio(0);
      if (lastT){
        #pragma unroll
        for (int kt=0;kt<4;++kt)
          #pragma unroll
          for (int r=0;r<4;++r)
            if (kv0 + kt*16 + 4*g + r > q0 + lr) sacc[kt][r] = -1e30f;
      }
      // --- lane-local online softmax (q=lr), FULL max (no defer) ---
      float tm = sacc[0][0];
      #pragma unroll
      for (int kt=0;kt<4;++kt)
        #pragma unroll
        for (int r=0;r<4;++r) tm = fmaxf(tm, sacc[kt][r]);
      tm = fmaxf(tm, __shfl_xor(tm, 16));
      tm = fmaxf(tm, __shfl_xor(tm, 32));
      const float mn = fmaxf(m_, tm);
      const float sc = __expf(m_ - mn);              // <=1, ==1 when max unchanged
      m_ = mn;
      #pragma unroll
      for (int kt=0;kt<4;++kt)
        #pragma unroll
        for (int r=0;r<4;++r) sacc[kt][r] = __expf(sacc[kt][r] - mn);
      // --- pack P to bf16 pairs (f2b) and gather B-operand fragments ---
      u32 pa[4], pb[4];
      #pragma unroll
      for (int kt=0;kt<4;++kt){
        pa[kt] = pk2(sacc[kt][0], sacc[kt][1]);
        pb[kt] = pk2(sacc[kt][2], sacc[kt][3]);
      }
      const int srcA = lr + 32*(g&1);
      const int srcB = srcA + 16;
      const bool hi = (g >= 2);
      union { s16x8 v; u32 u[4]; } P0, P1;
      {
        u32 a0 = (u32)__shfl((int)pa[0], srcA), a1 = (u32)__shfl((int)pa[1], srcA);
        u32 b0 = (u32)__shfl((int)pb[0], srcA), b1 = (u32)__shfl((int)pb[1], srcA);
        u32 c0 = (u32)__shfl((int)pa[0], srcB), c1 = (u32)__shfl((int)pa[1], srcB);
        u32 d0 = (u32)__shfl((int)pb[0], srcB), d1 = (u32)__shfl((int)pb[1], srcB);
        P0.u[0] = hi ? a1 : a0;  P0.u[1] = hi ? b1 : b0;
        P0.u[2] = hi ? c1 : c0;  P0.u[3] = hi ? d1 : d0;
      }
      {
        u32 a0 = (u32)__shfl((int)pa[2], srcA), a1 = (u32)__shfl((int)pa[3], srcA);
        u32 b0 = (u32)__shfl((int)pb[2], srcA), b1 = (u32)__shfl((int)pb[3], srcA);
        u32 c0 = (u32)__shfl((int)pa[2], srcB), c1 = (u32)__shfl((int)pa[3], srcB);
        u32 d0 = (u32)__shfl((int)pb[2], srcB), d1 = (u32)__shfl((int)pb[3], srcB);
        P1.u[0] = hi ? a1 : a0;  P1.u[1] = hi ? b1 : b0;
        P1.u[2] = hi ? c1 : c0;  P1.u[3] = hi ? d1 : d0;
      }
      const s16x8 pf0 = P0.v, pf1 = P1.v;
      // --- l-sum via ones-MFMA (same quantized P as PV) ---
      f32x4 ls = {};
      ls = __builtin_amdgcn_mfma_f32_16x16x32_bf16(ones, pf0, ls, 0,0,0);
      ls = __builtin_amdgcn_mfma_f32_16x16x32_bf16(ones, pf1, ls, 0,0,0);
      l_q = l_q*sc + ls[0];
      if (__any(sc != 1.0f)){
        #pragma unroll
        for (int dt=0;dt<8;++dt)
          #pragma unroll
          for (int r=0;r<4;++r) accO[dt][r] *= sc;
      }
      // --- PV: O^T += V^T @ P^T (V from LDS) ---
      const u16* Vsc = &Vs[cur][0];
      const int cb0 = (g*16) ^ sw;
      const int cb1 = (64 + g*16) ^ sw;
      __builtin_amdgcn_s_setprio(1);
      #pragma unroll
      for (int dt=0;dt<8;++dt){
        s16x8 vf0 = *(const s16x8*)(Vsc + (dt*16+lr)*64 + (cb0>>1));
        accO[dt] = __builtin_amdgcn_mfma_f32_16x16x32_bf16(vf0, pf0, accO[dt], 0,0,0);
        s16x8 vf1 = *(const s16x8*)(Vsc + (dt*16+lr)*64 + (cb1>>1));
        accO[dt] = __builtin_amdgcn_mfma_f32_16x16x32_bf16(vf1, pf1, accO[dt], 0,0,0);
      }
      __builtin_amdgcn_s_setprio(0);
      __syncthreads();          // staged t+1 visible; buffers swappable
      __builtin_amdgcn_sched_barrier(0);   // pin next-iter staging below barrier
      cur ^= 1;
    }
    // --- epilogue: transpose via LDS (aliases dead K staging), store ---
    const float linv = 1.0f / l_q;
    #pragma unroll
    for (int dt=0;dt<8;++dt)
      #pragma unroll
      for (int r=0;r<4;++r)
        Ol[w][lr][dt*16 + 4*g + r] = f2b(accO[dt][r] * linv);
    __syncthreads();
    #pragma unroll
    for (int p=0;p<4;++p){
      const int ql = p*4 + g;
      s16x8 ov = *(const s16x8*)(&Ol[w][ql][0] + lr*8);
      *(s16x8*)(Ob + (size_t)(q0+ql)*D_ + h*DK_ + lr*8) = ov;
    }
    __syncthreads();            // Ol reads done before next phase's STAGE_K
    __builtin_amdgcn_sched_barrier(0);
  }
  #undef STAGE_K
  #undef STAGE_V
}

// ---------------------------------------------------------------------------
extern "C" void kernel_launch(void* const* d_in, const int* in_sizes, int n_in,
                              void* d_out, int out_size, void* d_ws, size_t ws_size,
                              hipStream_t stream)
{
  const void* q   = d_in[0];
  const void* k   = d_in[1];
  const void* v   = d_in[2];
  const void* wq  = d_in[3];  const void* bq = d_in[4];
  const void* laq = d_in[5];  const void* lbq= d_in[6];
  const void* wk  = d_in[7];  const void* bk = d_in[8];
  const void* lak = d_in[9];  const void* lbk= d_in[10];
  const void* wv  = d_in[11]; const void* bv = d_in[12];
  const void* lav = d_in[13]; const void* lbv= d_in[14];
  const void* wo  = d_in[15]; const void* bo = d_in[16];
  const void* lao = d_in[17]; const void* lbo= d_in[18];

  char* ws = (char*)d_ws;
  int* flag = (int*)ws;
  char* base = ws + 256;
  const size_t MB = 1u<<20;
  u16* W   = (u16*)(base);            //  8 MiB, reused for each effW^T
  u16* Qb  = (u16*)(base +  8*MB);    // 16 MiB
  u16* Kb  = (u16*)(base + 24*MB);    // 16 MiB
  u16* Vb  = (u16*)(base + 40*MB);    // 16 MiB
  u16* VTb = (u16*)(base + 56*MB);    // 16 MiB  -> total 72 MiB + 256 B
  u16* Ob  = Vb;                      // V dead after transpose

  dim3 blk(256);
  dim3 gW(D_/64, D_/64);
  dim3 gG(D_/128, MROWS/128);
  detect32<<<1, blk, 0, stream>>>((const unsigned*)q, flag);
  prep_wt<<<gW, blk, 0, stream>>>(wq, laq, lbq, W, flag);
  gemm_bt<<<gG, blk, 0, stream>>>(q, W, bq, Qb, flag, 1, 0);
  prep_wt<<<gW, blk, 0, stream>>>(wk, lak, lbk, W, flag);
  gemm_bt<<<gG, blk, 0, stream>>>(k, W, bk, Kb, flag, 1, 0);
  prep_wt<<<gW, blk, 0, stream>>>(wv, lav, lbv, W, flag);
  gemm_bt<<<gG, blk, 0, stream>>>(v, W, bv, Vb, flag, 1, 0);
  transpose_v<<<dim3(S_/64, D_/64, B_), blk, 0, stream>>>(Vb, VTb);
  attn<<<dim3(S_/128, H_, B_), blk, 0, stream>>>(Qb, Kb, VTb, Ob);
  prep_wt<<<gW, blk, 0, stream>>>(wo, lao, lbo, W, flag);
  gemm_bt<<<gG, blk, 0, stream>>>(Ob, W, bo, d_out, flag, 0, 1);
}

// Round 17
// 350.260 us; speedup vs baseline: 1.2522x; 1.0835x over previous
//
#include <hip/hip_runtime.h>

// LoRA multi-head attention forward, B=2 S=2048 D=2048 H=16 dk=128 rank=8.
// Device dtype auto-detected (bf16 vs fp32) -> flag in ws; internal compute bf16.
// Pipeline: detect -> [cvt A -> prep effW^T -> GEMM] x3 (Q,K,V) -> V transpose
// -> causal flash attention -> prep effWo^T -> output GEMM.
// R17: A-operands pre-converted to bf16 once (cvt_bf16, same f2b rounding ->
// bit-identical), so ALL GEMMs use the fast glds16 staging path (R14 A/B:
// fp32 reg-staged 73us vs bf16 glds16 50.5us).  Gated on ws_size (88MB needed;
// falls back to R16's a32 path otherwise).  attn identical to R16.

#define B_   2
#define S_   2048
#define D_   2048
#define H_   16
#define DK_  128
#define MROWS (B_*S_)            // 4096
#define SCALE_ 0.08838834764831845f   // 1/sqrt(128)

using f32x4 = __attribute__((ext_vector_type(4))) float;
using s16x8 = __attribute__((ext_vector_type(8))) short;
typedef unsigned short u16;
typedef unsigned int u32;

__device__ __forceinline__ float b2f(u16 u){ union{unsigned u32v; float f;} x; x.u32v=((unsigned)u)<<16; return x.f; }
__device__ __forceinline__ u16 f2b(float f){ union{float f; unsigned u;} x; x.f=f; unsigned r=x.u+0x7fffu+((x.u>>16)&1u); return (u16)(r>>16); }
__device__ __forceinline__ u32 pk2(float lo, float hi){
  return ((u32)f2b(hi) << 16) | (u32)f2b(lo);
}

__device__ __forceinline__ void glds16(const void* g, void* l){
  __builtin_amdgcn_global_load_lds((const __attribute__((address_space(1))) unsigned int*)g,
                                   (__attribute__((address_space(3))) unsigned int*)l, 16, 0, 0);
}

// ---------------------------------------------------------------------------
__global__ void detect32(const unsigned* __restrict__ q, int* __restrict__ flag)
{
  __shared__ int s[4];
  int c = 0;
  for (int i = threadIdx.x; i < 4096; i += 256){
    unsigned u = q[i];
    unsigned e0 = (u >> 7) & 0xFFu;
    if (e0 >= 0x90u) ++c;
  }
  #pragma unroll
  for (int off = 32; off; off >>= 1) c += __shfl_down(c, off);
  if ((threadIdx.x & 63) == 0) s[threadIdx.x >> 6] = c;
  __syncthreads();
  if (threadIdx.x == 0) *flag = ((s[0]+s[1]+s[2]+s[3]) > 64) ? 1 : 0;
}

// ---------------------------------------------------------------------------
// A-operand conversion: fp32 -> bf16 (same f2b as the a32 staging path -> bit
// identical GEMM results) or straight copy when input already bf16.
// n = element count (multiple of 8).  grid-stride, 8 elems/thread/iter.
__global__ __launch_bounds__(256) void cvt_bf16(const void* __restrict__ src, u16* __restrict__ dst,
                                                const int* __restrict__ flagp, int n)
{
  const int f = *flagp;
  const int n8 = n >> 3;
  const int stride = gridDim.x * blockDim.x;
  if (f){
    const f32x4* s = (const f32x4*)src;
    for (int j = blockIdx.x*blockDim.x + threadIdx.x; j < n8; j += stride){
      f32x4 a = s[2*j], b = s[2*j+1];
      s16x8 o;
      #pragma unroll
      for (int r=0;r<4;++r){ o[r] = (short)f2b(a[r]); o[4+r] = (short)f2b(b[r]); }
      ((s16x8*)dst)[j] = o;
    }
  } else {
    const s16x8* s = (const s16x8*)src;
    for (int j = blockIdx.x*blockDim.x + threadIdx.x; j < n8; j += stride)
      ((s16x8*)dst)[j] = s[j];
  }
}

// ---------------------------------------------------------------------------
// effWT[n][k] = w[k][n] + sum_r la[k][r]*lb[r][n]
__global__ __launch_bounds__(256) void prep_wt(const void* __restrict__ w_, const void* __restrict__ la_,
                                               const void* __restrict__ lb_, u16* __restrict__ wt,
                                               const int* __restrict__ flagp)
{
  const int f32i = *flagp;
  __shared__ float tile[64][65];
  const int tid = threadIdx.x;
  const int k0 = blockIdx.x*64, n0 = blockIdx.y*64;
  const int c  = tid & 63;
  const int r0 = (tid >> 6) * 16;
  float lbv[8];
  if (f32i){
    const float* lb = (const float*)lb_;
    #pragma unroll
    for (int r=0;r<8;++r) lbv[r] = lb[(size_t)r*D_ + n0 + c];
  } else {
    const u16* lb = (const u16*)lb_;
    #pragma unroll
    for (int r=0;r<8;++r) lbv[r] = b2f(lb[(size_t)r*D_ + n0 + c]);
  }
  #pragma unroll
  for (int kk=0;kk<16;++kk){
    const int k = k0 + r0 + kk;
    float val;
    if (f32i){
      const float* w32 = (const float*)w_;  const float* la = (const float*)la_;
      val = w32[(size_t)k*D_ + n0 + c];
      f32x4 a0 = *(const f32x4*)(la + k*8);
      f32x4 a1 = *(const f32x4*)(la + k*8 + 4);
      #pragma unroll
      for (int r=0;r<4;++r) val += a0[r]*lbv[r];
      #pragma unroll
      for (int r=0;r<4;++r) val += a1[r]*lbv[4+r];
    } else {
      const u16* w16 = (const u16*)w_;  const u16* la = (const u16*)la_;
      val = b2f(w16[(size_t)k*D_ + n0 + c]);
      s16x8 av = *(const s16x8*)(la + k*8);
      #pragma unroll
      for (int r=0;r<8;++r) val += b2f((u16)av[r])*lbv[r];
    }
    tile[r0+kk][c] = val;
  }
  __syncthreads();
  #pragma unroll
  for (int nn=0;nn<16;++nn){
    const int nr = r0 + nn;
    wt[(size_t)(n0+nr)*D_ + k0 + c] = f2b(tile[c][nr]);
  }
}

// ---------------------------------------------------------------------------
__global__ __launch_bounds__(256) void transpose_v(const u16* __restrict__ V, u16* __restrict__ VT)
{
  __shared__ u16 tile[64][66];
  const int bz = blockIdx.z;
  const int s0 = blockIdx.x*64, d0 = blockIdx.y*64;
  const int tid = threadIdx.x;
  const u16* Vb = V + (size_t)bz*S_*D_;
  u16* VTb = VT + (size_t)bz*D_*S_;
  const int c = tid & 63, r0 = (tid>>6)*16;
  #pragma unroll
  for (int i=0;i<16;++i) tile[r0+i][c] = Vb[(size_t)(s0+r0+i)*D_ + d0 + c];
  __syncthreads();
  #pragma unroll
  for (int i=0;i<16;++i) VTb[(size_t)(d0+r0+i)*S_ + s0 + c] = tile[c][r0+i];
}

// ---------------------------------------------------------------------------
// C[m][n] = sum_k A[m][k]*BT[n][k] + bias[n].  M=4096, N=K=2048.
// 128x128 tile, BK=64, double-buffered prefetch, one barrier/iter.
// T1 chunked XCD swizzle (512%8==0, bijective).
// Swizzle invariant: LDS[row][c] = global[row][c ^ ((row&7)<<3)] (u16 units).
__global__ __launch_bounds__(256) void gemm_bt(const void* __restrict__ A_, const u16* __restrict__ BT,
                                               const void* __restrict__ bias_, void* __restrict__ C_,
                                               const int* __restrict__ flagp, int aF, int oF)
{
  constexpr int N = D_, K = D_;
  constexpr int NT = K/64;
  const int f = *flagp;
  const bool a32 = (aF != 0) && (f != 0);
  const bool o32 = (oF != 0) && (f != 0);
  __shared__ u16 As[2][128*64];      // 32 KB
  __shared__ u16 Bs[2][128*64];      // 32 KB
  const int tid = threadIdx.x;
  const int w = tid>>6, lane = tid&63, g = lane>>4, lr = lane&15;
  const int wm = w>>1, wn = w&1;
  // T1 XCD swizzle (requires nwg % 8 == 0; here 16*32=512)
  const unsigned flat = blockIdx.y*gridDim.x + blockIdx.x;
  const unsigned cpx  = (gridDim.x*gridDim.y) >> 3;        // 64
  const unsigned swz  = (flat & 7)*cpx + (flat >> 3);
  const int m0 = (int)(swz / gridDim.x) * 128;
  const int n0 = (int)(swz % gridDim.x) * 128;
  const int srow = lane>>3;                        // 0..7
  const int lcol = (lane&7)*8;                     // linear col, u16 units
  const int scol = lcol ^ (srow<<3);               // swizzled col
  const int rsw  = (lr&7)<<3;                      // read-side swizzle (u16)

  const float* Af = (const float*)A_;
  const u16*   Ab = (const u16*)A_;

  #define STAGE_B16(buf, k0_) do{ _Pragma("unroll")                                 \
    for (int jj=0;jj<4;++jj){ const int rb = w*32 + jj*8;                           \
      glds16(BT + (size_t)(n0+rb+srow)*K + (k0_) + scol, (void*)(&Bs[buf][0] + rb*64)); } }while(0)
  #define STAGE_A16(buf, k0_) do{ _Pragma("unroll")                                 \
    for (int jj=0;jj<4;++jj){ const int rb = w*32 + jj*8;                           \
      glds16(Ab + (size_t)(m0+rb+srow)*K + (k0_) + scol, (void*)(&As[buf][0] + rb*64)); } }while(0)
  #define LOAD_A32(k0_) do{ _Pragma("unroll")                                       \
    for (int jj=0;jj<4;++jj){                                                       \
      const float* src = Af + (size_t)(m0 + w*32 + jj*8 + srow)*K + (k0_) + lcol;   \
      ax0[jj] = *(const f32x4*)src; ax1[jj] = *(const f32x4*)(src + 4); } }while(0)
  #define WRITE_A32(buf) do{ _Pragma("unroll")                                      \
    for (int jj=0;jj<4;++jj){ const int rb = w*32 + jj*8; s16x8 pk;                 \
      _Pragma("unroll")                                                             \
      for (int i=0;i<4;++i){ pk[i]=(short)f2b(ax0[jj][i]); pk[4+i]=(short)f2b(ax1[jj][i]); } \
      *(s16x8*)(&As[buf][0] + (rb+srow)*64 + scol) = pk; } }while(0)

  f32x4 ax0[4], ax1[4];
  f32x4 acc[4][4] = {};

  if (a32){ LOAD_A32(0); WRITE_A32(0); } else { STAGE_A16(0, 0); }
  STAGE_B16(0, 0);
  __syncthreads();
  __builtin_amdgcn_sched_barrier(0);

  int cur = 0;
  for (int t=0; t<NT; ++t){
    const bool haveNext = (t+1 < NT);
    if (haveNext){
      if (a32) LOAD_A32((t+1)*64);              // issue early; write after compute
      else     STAGE_A16(cur^1, (t+1)*64);
      STAGE_B16(cur^1, (t+1)*64);
    }
    #pragma unroll
    for (int kk=0;kk<2;++kk){
      s16x8 af[4], bfr[4];
      #pragma unroll
      for (int i=0;i<4;++i) af[i]  = *(const s16x8*)(&As[cur][0] + (wm*64+i*16+lr)*64 + ((kk*32 + g*8) ^ rsw));
      #pragma unroll
      for (int i=0;i<4;++i) bfr[i] = *(const s16x8*)(&Bs[cur][0] + (wn*64+i*16+lr)*64 + ((kk*32 + g*8) ^ rsw));
      #pragma unroll
      for (int mi=0;mi<4;++mi)
        #pragma unroll
        for (int ni=0;ni<4;++ni)
          acc[mi][ni] = __builtin_amdgcn_mfma_f32_16x16x32_bf16(af[mi], bfr[ni], acc[mi][ni], 0,0,0);
    }
    if (haveNext && a32) WRITE_A32(cur^1);      // vmcnt wait lands after MFMAs
    __syncthreads();
    __builtin_amdgcn_sched_barrier(0);          // pin next-iter staging below barrier
    cur ^= 1;
  }
  #pragma unroll
  for (int ni=0;ni<4;++ni){
    const int n = n0 + wn*64 + ni*16 + lr;
    const float bv = f ? ((const float*)bias_)[n] : b2f(((const u16*)bias_)[n]);
    #pragma unroll
    for (int mi=0;mi<4;++mi){
      const int m = m0 + wm*64 + mi*16 + 4*g;
      #pragma unroll
      for (int r=0;r<4;++r){
        const float val = acc[mi][ni][r] + bv;
        if (o32) ((float*)C_)[(size_t)(m+r)*N + n] = val;
        else     ((u16*)C_)[(size_t)(m+r)*N + n] = f2b(val);
      }
    }
  }
  #undef STAGE_B16
  #undef STAGE_A16
  #undef LOAD_A32
  #undef WRITE_A32
}

// ---------------------------------------------------------------------------
// Causal flash attention.  grid (S/128, H, B), block 256 (4 waves x 16 q-rows).
// PAIRED blocks: block x handles q-tiles x and 31-x -> constant 33 tile-units;
// 512 blocks == 512 resident slots (2 blocks/CU) -> no tail.  K,V staged in
// LDS (dbuf, XOR swizzle, 1 barrier/tile + sched_barrier pin).  Swapped QK^T,
// lane-local softmax (q=lr, FULL online max), f2b pack + 16-shfl gather,
// ones-MFMA l-sum.
__global__ __launch_bounds__(256) void attn(const u16* __restrict__ Q, const u16* __restrict__ K,
                                            const u16* __restrict__ VT, u16* __restrict__ O)
{
  __shared__ u16  Ks[2][64*128];     // 32 KB, rows kv (256B), swizzled
  __shared__ u16  Vs[2][128*64];     // 32 KB, rows d (128B), swizzled
  u16 (*Ol)[16][136] = (u16(*)[16][136])(&Ks[0][0]);   // epilogue alias, dead staging

  const int tid = threadIdx.x;
  const int w = tid>>6, lane = tid&63, g = lane>>4, lr = lane&15;
  const int h = blockIdx.y, bz = blockIdx.z;
  const u16* Qb  = Q  + (size_t)bz*S_*D_;
  const u16* Kb  = K  + (size_t)bz*S_*D_;
  const u16* VTb = VT + (size_t)bz*D_*S_;
  u16* Ob = O + (size_t)bz*S_*D_;
  const int sw = (lr&7)<<4;                 // read-side swizzle (bytes)
  const int krow_l = lane>>4, kcol_l = (lane&15)*16;   // K staging lane map
  const int vrow_l = lane>>3, vcol_l = (lane&7)*16;    // V staging lane map

  s16x8 ones;
  #pragma unroll
  for (int i=0;i<8;++i) ones[i] = (short)0x3F80;       // bf16 1.0

  #define STAGE_K(buf, t_) do{ const int kv0s = (t_)*64;                            \
    _Pragma("unroll")                                                               \
    for (int jj=0;jj<4;++jj){ const int j = w*4 + jj; const int r = j*4 + krow_l;   \
      const int cb = kcol_l ^ ((r&7)<<4);                                           \
      glds16(Kb + (size_t)(kv0s + r)*D_ + h*DK_ + (cb>>1), (void*)(&Ks[buf][0] + j*512)); } }while(0)
  #define STAGE_V(buf, t_) do{ const int kv0s = (t_)*64;                            \
    _Pragma("unroll")                                                               \
    for (int jj=0;jj<4;++jj){ const int j = w*4 + jj; const int r = j*8 + vrow_l;   \
      const int cb = vcol_l ^ ((r&7)<<4);                                           \
      glds16(VTb + (size_t)(h*DK_ + r)*S_ + kv0s + (cb>>1), (void*)(&Vs[buf][0] + j*512)); } }while(0)

  for (int qq=0; qq<2; ++qq){
    const int qt = qq ? (int)(S_/64 - 1 - blockIdx.x) : (int)blockIdx.x;
    const int q0 = qt*64 + w*16;
    const int nt = qt + 1;

    // Q fragments, pre-scaled by 1/sqrt(dk)
    s16x8 qf[4];
    #pragma unroll
    for (int dc=0;dc<4;++dc){
      s16x8 t = *(const s16x8*)(Qb + (size_t)(q0+lr)*D_ + h*DK_ + dc*32 + g*8);
      #pragma unroll
      for (int i=0;i<8;++i) t[i] = (short)f2b(b2f((u16)t[i]) * SCALE_);
      qf[dc] = t;
    }
    float m_  = -1e30f;              // running max for q-row lr (lane-local)
    float l_q = 0.f;                 // row-sum for q-row lr (lane-local)
    f32x4 accO[8] = {};              // O^T[d=dt*16+4g+r][q=lr], fp32

    STAGE_K(0, 0); STAGE_V(0, 0);
    __syncthreads();
    __builtin_amdgcn_sched_barrier(0);
    int cur = 0;
    for (int t=0;t<nt;++t){
      const int kv0 = t*64;
      const bool lastT = (t == nt-1);
      if (!lastT){ STAGE_K(cur^1, t+1); STAGE_V(cur^1, t+1); }
      // --- QK^T (swapped): sacc[kt][r] = S[q=lr][key=kt*16+4g+r] ---
      const u16* Ksc = &Ks[cur][0];
      f32x4 sacc[4] = {};
      __builtin_amdgcn_s_setprio(1);
      #pragma unroll
      for (int dc=0;dc<4;++dc){
        const int cb = (dc*64 + g*16) ^ sw;
        #pragma unroll
        for (int kt=0;kt<4;++kt){
          s16x8 kf = *(const s16x8*)(Ksc + (kt*16+lr)*128 + (cb>>1));
          sacc[kt] = __builtin_amdgcn_mfma_f32_16x16x32_bf16(kf, qf[dc], sacc[kt], 0,0,0);
        }
      }
      __builtin_amdgcn_s_setprio(0);
      if (lastT){
        #pragma unroll
        for (int kt=0;kt<4;++kt)
          #pragma unroll
          for (int r=0;r<4;++r)
            if (kv0 + kt*16 + 4*g + r > q0 + lr) sacc[kt][r] = -1e30f;
      }
      // --- lane-local online softmax (q=lr), FULL max (no defer) ---
      float tm = sacc[0][0];
      #pragma unroll
      for (int kt=0;kt<4;++kt)
        #pragma unroll
        for (int r=0;r<4;++r) tm = fmaxf(tm, sacc[kt][r]);
      tm = fmaxf(tm, __shfl_xor(tm, 16));
      tm = fmaxf(tm, __shfl_xor(tm, 32));
      const float mn = fmaxf(m_, tm);
      const float sc = __expf(m_ - mn);              // <=1, ==1 when max unchanged
      m_ = mn;
      #pragma unroll
      for (int kt=0;kt<4;++kt)
        #pragma unroll
        for (int r=0;r<4;++r) sacc[kt][r] = __expf(sacc[kt][r] - mn);
      // --- pack P to bf16 pairs (f2b) and gather B-operand fragments ---
      u32 pa[4], pb[4];
      #pragma unroll
      for (int kt=0;kt<4;++kt){
        pa[kt] = pk2(sacc[kt][0], sacc[kt][1]);
        pb[kt] = pk2(sacc[kt][2], sacc[kt][3]);
      }
      const int srcA = lr + 32*(g&1);
      const int srcB = srcA + 16;
      const bool hi = (g >= 2);
      union { s16x8 v; u32 u[4]; } P0, P1;
      {
        u32 a0 = (u32)__shfl((int)pa[0], srcA), a1 = (u32)__shfl((int)pa[1], srcA);
        u32 b0 = (u32)__shfl((int)pb[0], srcA), b1 = (u32)__shfl((int)pb[1], srcA);
        u32 c0 = (u32)__shfl((int)pa[0], srcB), c1 = (u32)__shfl((int)pa[1], srcB);
        u32 d0 = (u32)__shfl((int)pb[0], srcB), d1 = (u32)__shfl((int)pb[1], srcB);
        P0.u[0] = hi ? a1 : a0;  P0.u[1] = hi ? b1 : b0;
        P0.u[2] = hi ? c1 : c0;  P0.u[3] = hi ? d1 : d0;
      }
      {
        u32 a0 = (u32)__shfl((int)pa[2], srcA), a1 = (u32)__shfl((int)pa[3], srcA);
        u32 b0 = (u32)__shfl((int)pb[2], srcA), b1 = (u32)__shfl((int)pb[3], srcA);
        u32 c0 = (u32)__shfl((int)pa[2], srcB), c1 = (u32)__shfl((int)pa[3], srcB);
        u32 d0 = (u32)__shfl((int)pb[2], srcB), d1 = (u32)__shfl((int)pb[3], srcB);
        P1.u[0] = hi ? a1 : a0;  P1.u[1] = hi ? b1 : b0;
        P1.u[2] = hi ? c1 : c0;  P1.u[3] = hi ? d1 : d0;
      }
      const s16x8 pf0 = P0.v, pf1 = P1.v;
      // --- l-sum via ones-MFMA (same quantized P as PV) ---
      f32x4 ls = {};
      ls = __builtin_amdgcn_mfma_f32_16x16x32_bf16(ones, pf0, ls, 0,0,0);
      ls = __builtin_amdgcn_mfma_f32_16x16x32_bf16(ones, pf1, ls, 0,0,0);
      l_q = l_q*sc + ls[0];
      if (__any(sc != 1.0f)){
        #pragma unroll
        for (int dt=0;dt<8;++dt)
          #pragma unroll
          for (int r=0;r<4;++r) accO[dt][r] *= sc;
      }
      // --- PV: O^T += V^T @ P^T (V from LDS) ---
      const u16* Vsc = &Vs[cur][0];
      const int cb0 = (g*16) ^ sw;
      const int cb1 = (64 + g*16) ^ sw;
      __builtin_amdgcn_s_setprio(1);
      #pragma unroll
      for (int dt=0;dt<8;++dt){
        s16x8 vf0 = *(const s16x8*)(Vsc + (dt*16+lr)*64 + (cb0>>1));
        accO[dt] = __builtin_amdgcn_mfma_f32_16x16x32_bf16(vf0, pf0, accO[dt], 0,0,0);
        s16x8 vf1 = *(const s16x8*)(Vsc + (dt*16+lr)*64 + (cb1>>1));
        accO[dt] = __builtin_amdgcn_mfma_f32_16x16x32_bf16(vf1, pf1, accO[dt], 0,0,0);
      }
      __builtin_amdgcn_s_setprio(0);
      __syncthreads();          // staged t+1 visible; buffers swappable
      __builtin_amdgcn_sched_barrier(0);   // pin next-iter staging below barrier
      cur ^= 1;
    }
    // --- epilogue: transpose via LDS (aliases dead K staging), store ---
    const float linv = 1.0f / l_q;
    #pragma unroll
    for (int dt=0;dt<8;++dt)
      #pragma unroll
      for (int r=0;r<4;++r)
        Ol[w][lr][dt*16 + 4*g + r] = f2b(accO[dt][r] * linv);
    __syncthreads();
    #pragma unroll
    for (int p=0;p<4;++p){
      const int ql = p*4 + g;
      s16x8 ov = *(const s16x8*)(&Ol[w][ql][0] + lr*8);
      *(s16x8*)(Ob + (size_t)(q0+ql)*D_ + h*DK_ + lr*8) = ov;
    }
    __syncthreads();            // Ol reads done before next phase's STAGE_K
    __builtin_amdgcn_sched_barrier(0);
  }
  #undef STAGE_K
  #undef STAGE_V
}

// ---------------------------------------------------------------------------
extern "C" void kernel_launch(void* const* d_in, const int* in_sizes, int n_in,
                              void* d_out, int out_size, void* d_ws, size_t ws_size,
                              hipStream_t stream)
{
  const void* q   = d_in[0];
  const void* k   = d_in[1];
  const void* v   = d_in[2];
  const void* wq  = d_in[3];  const void* bq = d_in[4];
  const void* laq = d_in[5];  const void* lbq= d_in[6];
  const void* wk  = d_in[7];  const void* bk = d_in[8];
  const void* lak = d_in[9];  const void* lbk= d_in[10];
  const void* wv  = d_in[11]; const void* bv = d_in[12];
  const void* lav = d_in[13]; const void* lbv= d_in[14];
  const void* wo  = d_in[15]; const void* bo = d_in[16];
  const void* lao = d_in[17]; const void* lbo= d_in[18];

  char* ws = (char*)d_ws;
  int* flag = (int*)ws;
  char* base = ws + 256;
  const size_t MB = 1u<<20;
  u16* W   = (u16*)(base);            //  8 MiB, reused for each effW^T
  u16* Qb  = (u16*)(base +  8*MB);    // 16 MiB
  u16* Kb  = (u16*)(base + 24*MB);    // 16 MiB
  u16* Vb  = (u16*)(base + 40*MB);    // 16 MiB
  u16* VTb = (u16*)(base + 56*MB);    // 16 MiB
  u16* Ob  = Vb;                      // V dead after transpose
  u16* X   = (u16*)(base + 72*MB);    // 16 MiB, converted A (reused Q->K->V)
  const bool useCvt = ws_size >= (size_t)(88*MB + 256);

  dim3 blk(256);
  dim3 gW(D_/64, D_/64);
  dim3 gG(D_/128, MROWS/128);
  const int nElems = MROWS * D_;      // 8M elements per activation
  detect32<<<1, blk, 0, stream>>>((const unsigned*)q, flag);
  prep_wt<<<gW, blk, 0, stream>>>(wq, laq, lbq, W, flag);
  if (useCvt){
    cvt_bf16<<<2048, blk, 0, stream>>>(q, X, flag, nElems);
    gemm_bt<<<gG, blk, 0, stream>>>(X, W, bq, Qb, flag, 0, 0);
  } else {
    gemm_bt<<<gG, blk, 0, stream>>>(q, W, bq, Qb, flag, 1, 0);
  }
  prep_wt<<<gW, blk, 0, stream>>>(wk, lak, lbk, W, flag);
  if (useCvt){
    cvt_bf16<<<2048, blk, 0, stream>>>(k, X, flag, nElems);
    gemm_bt<<<gG, blk, 0, stream>>>(X, W, bk, Kb, flag, 0, 0);
  } else {
    gemm_bt<<<gG, blk, 0, stream>>>(k, W, bk, Kb, flag, 1, 0);
  }
  prep_wt<<<gW, blk, 0, stream>>>(wv, lav, lbv, W, flag);
  if (useCvt){
    cvt_bf16<<<2048, blk, 0, stream>>>(v, X, flag, nElems);
    gemm_bt<<<gG, blk, 0, stream>>>(X, W, bv, Vb, flag, 0, 0);
  } else {
    gemm_bt<<<gG, blk, 0, stream>>>(v, W, bv, Vb, flag, 1, 0);
  }
  transpose_v<<<dim3(S_/64, D_/64, B_), blk, 0, stream>>>(Vb, VTb);
  attn<<<dim3(S_/128, H_, B_), blk, 0, stream>>>(Qb, Kb, VTb, Ob);
  prep_wt<<<gW, blk, 0, stream>>>(wo, lao, lbo, W, flag);
  gemm_bt<<<gG, blk, 0, stream>>>(Ob, W, bo, d_out, flag, 0, 1);
}

// Round 18
// 332.553 us; speedup vs baseline: 1.3189x; 1.0532x over previous
//
#include <hip/hip_runtime.h>

// LoRA multi-head attention forward, B=2 S=2048 D=2048 H=16 dk=128 rank=8.
// Device dtype auto-detected (bf16 vs fp32) -> flag in ws; internal compute bf16.
// Pipeline: detect -> [cvt A -> prep effW^T -> GEMM] x3 (Q,K,V) -> V transpose
// -> causal flash attention -> prep effWo^T -> output GEMM.
// R18: attn re-gains the XCD-chunked work remap (64 consecutive works = 4
// complete (h,bz) groups per XCD -> same-head KV re-reads hit the local L2).
// R15's failure was the since-fixed hoist race (R16), not the remap.
// Everything else identical to R17.

#define B_   2
#define S_   2048
#define D_   2048
#define H_   16
#define DK_  128
#define MROWS (B_*S_)            // 4096
#define SCALE_ 0.08838834764831845f   // 1/sqrt(128)

using f32x4 = __attribute__((ext_vector_type(4))) float;
using s16x8 = __attribute__((ext_vector_type(8))) short;
typedef unsigned short u16;
typedef unsigned int u32;

__device__ __forceinline__ float b2f(u16 u){ union{unsigned u32v; float f;} x; x.u32v=((unsigned)u)<<16; return x.f; }
__device__ __forceinline__ u16 f2b(float f){ union{float f; unsigned u;} x; x.f=f; unsigned r=x.u+0x7fffu+((x.u>>16)&1u); return (u16)(r>>16); }
__device__ __forceinline__ u32 pk2(float lo, float hi){
  return ((u32)f2b(hi) << 16) | (u32)f2b(lo);
}

__device__ __forceinline__ void glds16(const void* g, void* l){
  __builtin_amdgcn_global_load_lds((const __attribute__((address_space(1))) unsigned int*)g,
                                   (__attribute__((address_space(3))) unsigned int*)l, 16, 0, 0);
}

// ---------------------------------------------------------------------------
__global__ void detect32(const unsigned* __restrict__ q, int* __restrict__ flag)
{
  __shared__ int s[4];
  int c = 0;
  for (int i = threadIdx.x; i < 4096; i += 256){
    unsigned u = q[i];
    unsigned e0 = (u >> 7) & 0xFFu;
    if (e0 >= 0x90u) ++c;
  }
  #pragma unroll
  for (int off = 32; off; off >>= 1) c += __shfl_down(c, off);
  if ((threadIdx.x & 63) == 0) s[threadIdx.x >> 6] = c;
  __syncthreads();
  if (threadIdx.x == 0) *flag = ((s[0]+s[1]+s[2]+s[3]) > 64) ? 1 : 0;
}

// ---------------------------------------------------------------------------
// A-operand conversion: fp32 -> bf16 (same f2b as the a32 staging path) or
// straight copy when input already bf16.  grid-stride, 8 elems/thread/iter.
__global__ __launch_bounds__(256) void cvt_bf16(const void* __restrict__ src, u16* __restrict__ dst,
                                                const int* __restrict__ flagp, int n)
{
  const int f = *flagp;
  const int n8 = n >> 3;
  const int stride = gridDim.x * blockDim.x;
  if (f){
    const f32x4* s = (const f32x4*)src;
    for (int j = blockIdx.x*blockDim.x + threadIdx.x; j < n8; j += stride){
      f32x4 a = s[2*j], b = s[2*j+1];
      s16x8 o;
      #pragma unroll
      for (int r=0;r<4;++r){ o[r] = (short)f2b(a[r]); o[4+r] = (short)f2b(b[r]); }
      ((s16x8*)dst)[j] = o;
    }
  } else {
    const s16x8* s = (const s16x8*)src;
    for (int j = blockIdx.x*blockDim.x + threadIdx.x; j < n8; j += stride)
      ((s16x8*)dst)[j] = s[j];
  }
}

// ---------------------------------------------------------------------------
// effWT[n][k] = w[k][n] + sum_r la[k][r]*lb[r][n]
__global__ __launch_bounds__(256) void prep_wt(const void* __restrict__ w_, const void* __restrict__ la_,
                                               const void* __restrict__ lb_, u16* __restrict__ wt,
                                               const int* __restrict__ flagp)
{
  const int f32i = *flagp;
  __shared__ float tile[64][65];
  const int tid = threadIdx.x;
  const int k0 = blockIdx.x*64, n0 = blockIdx.y*64;
  const int c  = tid & 63;
  const int r0 = (tid >> 6) * 16;
  float lbv[8];
  if (f32i){
    const float* lb = (const float*)lb_;
    #pragma unroll
    for (int r=0;r<8;++r) lbv[r] = lb[(size_t)r*D_ + n0 + c];
  } else {
    const u16* lb = (const u16*)lb_;
    #pragma unroll
    for (int r=0;r<8;++r) lbv[r] = b2f(lb[(size_t)r*D_ + n0 + c]);
  }
  #pragma unroll
  for (int kk=0;kk<16;++kk){
    const int k = k0 + r0 + kk;
    float val;
    if (f32i){
      const float* w32 = (const float*)w_;  const float* la = (const float*)la_;
      val = w32[(size_t)k*D_ + n0 + c];
      f32x4 a0 = *(const f32x4*)(la + k*8);
      f32x4 a1 = *(const f32x4*)(la + k*8 + 4);
      #pragma unroll
      for (int r=0;r<4;++r) val += a0[r]*lbv[r];
      #pragma unroll
      for (int r=0;r<4;++r) val += a1[r]*lbv[4+r];
    } else {
      const u16* w16 = (const u16*)w_;  const u16* la = (const u16*)la_;
      val = b2f(w16[(size_t)k*D_ + n0 + c]);
      s16x8 av = *(const s16x8*)(la + k*8);
      #pragma unroll
      for (int r=0;r<8;++r) val += b2f((u16)av[r])*lbv[r];
    }
    tile[r0+kk][c] = val;
  }
  __syncthreads();
  #pragma unroll
  for (int nn=0;nn<16;++nn){
    const int nr = r0 + nn;
    wt[(size_t)(n0+nr)*D_ + k0 + c] = f2b(tile[c][nr]);
  }
}

// ---------------------------------------------------------------------------
__global__ __launch_bounds__(256) void transpose_v(const u16* __restrict__ V, u16* __restrict__ VT)
{
  __shared__ u16 tile[64][66];
  const int bz = blockIdx.z;
  const int s0 = blockIdx.x*64, d0 = blockIdx.y*64;
  const int tid = threadIdx.x;
  const u16* Vb = V + (size_t)bz*S_*D_;
  u16* VTb = VT + (size_t)bz*D_*S_;
  const int c = tid & 63, r0 = (tid>>6)*16;
  #pragma unroll
  for (int i=0;i<16;++i) tile[r0+i][c] = Vb[(size_t)(s0+r0+i)*D_ + d0 + c];
  __syncthreads();
  #pragma unroll
  for (int i=0;i<16;++i) VTb[(size_t)(d0+r0+i)*S_ + s0 + c] = tile[c][r0+i];
}

// ---------------------------------------------------------------------------
// C[m][n] = sum_k A[m][k]*BT[n][k] + bias[n].  M=4096, N=K=2048.
// 128x128 tile, BK=64, double-buffered prefetch, one barrier/iter.
// T1 chunked XCD swizzle (512%8==0, bijective).
// Swizzle invariant: LDS[row][c] = global[row][c ^ ((row&7)<<3)] (u16 units).
__global__ __launch_bounds__(256) void gemm_bt(const void* __restrict__ A_, const u16* __restrict__ BT,
                                               const void* __restrict__ bias_, void* __restrict__ C_,
                                               const int* __restrict__ flagp, int aF, int oF)
{
  constexpr int N = D_, K = D_;
  constexpr int NT = K/64;
  const int f = *flagp;
  const bool a32 = (aF != 0) && (f != 0);
  const bool o32 = (oF != 0) && (f != 0);
  __shared__ u16 As[2][128*64];      // 32 KB
  __shared__ u16 Bs[2][128*64];      // 32 KB
  const int tid = threadIdx.x;
  const int w = tid>>6, lane = tid&63, g = lane>>4, lr = lane&15;
  const int wm = w>>1, wn = w&1;
  // T1 XCD swizzle (requires nwg % 8 == 0; here 16*32=512)
  const unsigned flat = blockIdx.y*gridDim.x + blockIdx.x;
  const unsigned cpx  = (gridDim.x*gridDim.y) >> 3;        // 64
  const unsigned swz  = (flat & 7)*cpx + (flat >> 3);
  const int m0 = (int)(swz / gridDim.x) * 128;
  const int n0 = (int)(swz % gridDim.x) * 128;
  const int srow = lane>>3;                        // 0..7
  const int lcol = (lane&7)*8;                     // linear col, u16 units
  const int scol = lcol ^ (srow<<3);               // swizzled col
  const int rsw  = (lr&7)<<3;                      // read-side swizzle (u16)

  const float* Af = (const float*)A_;
  const u16*   Ab = (const u16*)A_;

  #define STAGE_B16(buf, k0_) do{ _Pragma("unroll")                                 \
    for (int jj=0;jj<4;++jj){ const int rb = w*32 + jj*8;                           \
      glds16(BT + (size_t)(n0+rb+srow)*K + (k0_) + scol, (void*)(&Bs[buf][0] + rb*64)); } }while(0)
  #define STAGE_A16(buf, k0_) do{ _Pragma("unroll")                                 \
    for (int jj=0;jj<4;++jj){ const int rb = w*32 + jj*8;                           \
      glds16(Ab + (size_t)(m0+rb+srow)*K + (k0_) + scol, (void*)(&As[buf][0] + rb*64)); } }while(0)
  #define LOAD_A32(k0_) do{ _Pragma("unroll")                                       \
    for (int jj=0;jj<4;++jj){                                                       \
      const float* src = Af + (size_t)(m0 + w*32 + jj*8 + srow)*K + (k0_) + lcol;   \
      ax0[jj] = *(const f32x4*)src; ax1[jj] = *(const f32x4*)(src + 4); } }while(0)
  #define WRITE_A32(buf) do{ _Pragma("unroll")                                      \
    for (int jj=0;jj<4;++jj){ const int rb = w*32 + jj*8; s16x8 pk;                 \
      _Pragma("unroll")                                                             \
      for (int i=0;i<4;++i){ pk[i]=(short)f2b(ax0[jj][i]); pk[4+i]=(short)f2b(ax1[jj][i]); } \
      *(s16x8*)(&As[buf][0] + (rb+srow)*64 + scol) = pk; } }while(0)

  f32x4 ax0[4], ax1[4];
  f32x4 acc[4][4] = {};

  if (a32){ LOAD_A32(0); WRITE_A32(0); } else { STAGE_A16(0, 0); }
  STAGE_B16(0, 0);
  __syncthreads();
  __builtin_amdgcn_sched_barrier(0);

  int cur = 0;
  for (int t=0; t<NT; ++t){
    const bool haveNext = (t+1 < NT);
    if (haveNext){
      if (a32) LOAD_A32((t+1)*64);              // issue early; write after compute
      else     STAGE_A16(cur^1, (t+1)*64);
      STAGE_B16(cur^1, (t+1)*64);
    }
    #pragma unroll
    for (int kk=0;kk<2;++kk){
      s16x8 af[4], bfr[4];
      #pragma unroll
      for (int i=0;i<4;++i) af[i]  = *(const s16x8*)(&As[cur][0] + (wm*64+i*16+lr)*64 + ((kk*32 + g*8) ^ rsw));
      #pragma unroll
      for (int i=0;i<4;++i) bfr[i] = *(const s16x8*)(&Bs[cur][0] + (wn*64+i*16+lr)*64 + ((kk*32 + g*8) ^ rsw));
      #pragma unroll
      for (int mi=0;mi<4;++mi)
        #pragma unroll
        for (int ni=0;ni<4;++ni)
          acc[mi][ni] = __builtin_amdgcn_mfma_f32_16x16x32_bf16(af[mi], bfr[ni], acc[mi][ni], 0,0,0);
    }
    if (haveNext && a32) WRITE_A32(cur^1);      // vmcnt wait lands after MFMAs
    __syncthreads();
    __builtin_amdgcn_sched_barrier(0);          // pin next-iter staging below barrier
    cur ^= 1;
  }
  #pragma unroll
  for (int ni=0;ni<4;++ni){
    const int n = n0 + wn*64 + ni*16 + lr;
    const float bv = f ? ((const float*)bias_)[n] : b2f(((const u16*)bias_)[n]);
    #pragma unroll
    for (int mi=0;mi<4;++mi){
      const int m = m0 + wm*64 + mi*16 + 4*g;
      #pragma unroll
      for (int r=0;r<4;++r){
        const float val = acc[mi][ni][r] + bv;
        if (o32) ((float*)C_)[(size_t)(m+r)*N + n] = val;
        else     ((u16*)C_)[(size_t)(m+r)*N + n] = f2b(val);
      }
    }
  }
  #undef STAGE_B16
  #undef STAGE_A16
  #undef LOAD_A32
  #undef WRITE_A32
}

// ---------------------------------------------------------------------------
// Causal flash attention.  grid (S/128, H, B), block 256 (4 waves x 16 q-rows).
// PAIRED blocks: work x handles q-tiles x and 31-x -> constant 33 tile-units;
// 512 blocks == 512 resident slots.  XCD-chunked remap: 64 consecutive works
// (4 complete (h,bz) groups) per XCD -> same-head KV re-reads hit local L2.
// K,V staged in LDS (dbuf, XOR swizzle, 1 barrier/tile + sched_barrier pin).
// Swapped QK^T, lane-local softmax (q=lr, FULL online max), f2b pack +
// 16-shfl gather, ones-MFMA l-sum.
__global__ __launch_bounds__(256) void attn(const u16* __restrict__ Q, const u16* __restrict__ K,
                                            const u16* __restrict__ VT, u16* __restrict__ O)
{
  __shared__ u16  Ks[2][64*128];     // 32 KB, rows kv (256B), swizzled
  __shared__ u16  Vs[2][128*64];     // 32 KB, rows d (128B), swizzled
  u16 (*Ol)[16][136] = (u16(*)[16][136])(&Ks[0][0]);   // epilogue alias, dead staging

  const int tid = threadIdx.x;
  const int w = tid>>6, lane = tid&63, g = lane>>4, lr = lane&15;
  // XCD-chunked work remap (T1): rr-dispatch flat -> 64-chunk per XCD
  const unsigned flat = blockIdx.x + gridDim.x*(blockIdx.y + gridDim.y*blockIdx.z);
  const unsigned work = (flat & 7)*64u + (flat >> 3);   // bijective on [0,512)
  const int xp = (int)(work & 15);          // pair index 0..15
  const int h  = (int)((work >> 4) & 15);   // head
  const int bz = (int)(work >> 8);          // batch
  const u16* Qb  = Q  + (size_t)bz*S_*D_;
  const u16* Kb  = K  + (size_t)bz*S_*D_;
  const u16* VTb = VT + (size_t)bz*D_*S_;
  u16* Ob = O + (size_t)bz*S_*D_;
  const int sw = (lr&7)<<4;                 // read-side swizzle (bytes)
  const int krow_l = lane>>4, kcol_l = (lane&15)*16;   // K staging lane map
  const int vrow_l = lane>>3, vcol_l = (lane&7)*16;    // V staging lane map

  s16x8 ones;
  #pragma unroll
  for (int i=0;i<8;++i) ones[i] = (short)0x3F80;       // bf16 1.0

  #define STAGE_K(buf, t_) do{ const int kv0s = (t_)*64;                            \
    _Pragma("unroll")                                                               \
    for (int jj=0;jj<4;++jj){ const int j = w*4 + jj; const int r = j*4 + krow_l;   \
      const int cb = kcol_l ^ ((r&7)<<4);                                           \
      glds16(Kb + (size_t)(kv0s + r)*D_ + h*DK_ + (cb>>1), (void*)(&Ks[buf][0] + j*512)); } }while(0)
  #define STAGE_V(buf, t_) do{ const int kv0s = (t_)*64;                            \
    _Pragma("unroll")                                                               \
    for (int jj=0;jj<4;++jj){ const int j = w*4 + jj; const int r = j*8 + vrow_l;   \
      const int cb = vcol_l ^ ((r&7)<<4);                                           \
      glds16(VTb + (size_t)(h*DK_ + r)*S_ + kv0s + (cb>>1), (void*)(&Vs[buf][0] + j*512)); } }while(0)

  for (int qq=0; qq<2; ++qq){
    const int qt = qq ? (int)(S_/64 - 1 - xp) : xp;
    const int q0 = qt*64 + w*16;
    const int nt = qt + 1;

    // Q fragments, pre-scaled by 1/sqrt(dk)
    s16x8 qf[4];
    #pragma unroll
    for (int dc=0;dc<4;++dc){
      s16x8 t = *(const s16x8*)(Qb + (size_t)(q0+lr)*D_ + h*DK_ + dc*32 + g*8);
      #pragma unroll
      for (int i=0;i<8;++i) t[i] = (short)f2b(b2f((u16)t[i]) * SCALE_);
      qf[dc] = t;
    }
    float m_  = -1e30f;              // running max for q-row lr (lane-local)
    float l_q = 0.f;                 // row-sum for q-row lr (lane-local)
    f32x4 accO[8] = {};              // O^T[d=dt*16+4g+r][q=lr], fp32

    STAGE_K(0, 0); STAGE_V(0, 0);
    __syncthreads();
    __builtin_amdgcn_sched_barrier(0);
    int cur = 0;
    for (int t=0;t<nt;++t){
      const int kv0 = t*64;
      const bool lastT = (t == nt-1);
      if (!lastT){ STAGE_K(cur^1, t+1); STAGE_V(cur^1, t+1); }
      // --- QK^T (swapped): sacc[kt][r] = S[q=lr][key=kt*16+4g+r] ---
      const u16* Ksc = &Ks[cur][0];
      f32x4 sacc[4] = {};
      __builtin_amdgcn_s_setprio(1);
      #pragma unroll
      for (int dc=0;dc<4;++dc){
        const int cb = (dc*64 + g*16) ^ sw;
        #pragma unroll
        for (int kt=0;kt<4;++kt){
          s16x8 kf = *(const s16x8*)(Ksc + (kt*16+lr)*128 + (cb>>1));
          sacc[kt] = __builtin_amdgcn_mfma_f32_16x16x32_bf16(kf, qf[dc], sacc[kt], 0,0,0);
        }
      }
      __builtin_amdgcn_s_setprio(0);
      if (lastT){
        #pragma unroll
        for (int kt=0;kt<4;++kt)
          #pragma unroll
          for (int r=0;r<4;++r)
            if (kv0 + kt*16 + 4*g + r > q0 + lr) sacc[kt][r] = -1e30f;
      }
      // --- lane-local online softmax (q=lr), FULL max (no defer) ---
      float tm = sacc[0][0];
      #pragma unroll
      for (int kt=0;kt<4;++kt)
        #pragma unroll
        for (int r=0;r<4;++r) tm = fmaxf(tm, sacc[kt][r]);
      tm = fmaxf(tm, __shfl_xor(tm, 16));
      tm = fmaxf(tm, __shfl_xor(tm, 32));
      const float mn = fmaxf(m_, tm);
      const float sc = __expf(m_ - mn);              // <=1, ==1 when max unchanged
      m_ = mn;
      #pragma unroll
      for (int kt=0;kt<4;++kt)
        #pragma unroll
        for (int r=0;r<4;++r) sacc[kt][r] = __expf(sacc[kt][r] - mn);
      // --- pack P to bf16 pairs (f2b) and gather B-operand fragments ---
      u32 pa[4], pb[4];
      #pragma unroll
      for (int kt=0;kt<4;++kt){
        pa[kt] = pk2(sacc[kt][0], sacc[kt][1]);
        pb[kt] = pk2(sacc[kt][2], sacc[kt][3]);
      }
      const int srcA = lr + 32*(g&1);
      const int srcB = srcA + 16;
      const bool hi = (g >= 2);
      union { s16x8 v; u32 u[4]; } P0, P1;
      {
        u32 a0 = (u32)__shfl((int)pa[0], srcA), a1 = (u32)__shfl((int)pa[1], srcA);
        u32 b0 = (u32)__shfl((int)pb[0], srcA), b1 = (u32)__shfl((int)pb[1], srcA);
        u32 c0 = (u32)__shfl((int)pa[0], srcB), c1 = (u32)__shfl((int)pa[1], srcB);
        u32 d0 = (u32)__shfl((int)pb[0], srcB), d1 = (u32)__shfl((int)pb[1], srcB);
        P0.u[0] = hi ? a1 : a0;  P0.u[1] = hi ? b1 : b0;
        P0.u[2] = hi ? c1 : c0;  P0.u[3] = hi ? d1 : d0;
      }
      {
        u32 a0 = (u32)__shfl((int)pa[2], srcA), a1 = (u32)__shfl((int)pa[3], srcA);
        u32 b0 = (u32)__shfl((int)pb[2], srcA), b1 = (u32)__shfl((int)pb[3], srcA);
        u32 c0 = (u32)__shfl((int)pa[2], srcB), c1 = (u32)__shfl((int)pa[3], srcB);
        u32 d0 = (u32)__shfl((int)pb[2], srcB), d1 = (u32)__shfl((int)pb[3], srcB);
        P1.u[0] = hi ? a1 : a0;  P1.u[1] = hi ? b1 : b0;
        P1.u[2] = hi ? c1 : c0;  P1.u[3] = hi ? d1 : d0;
      }
      const s16x8 pf0 = P0.v, pf1 = P1.v;
      // --- l-sum via ones-MFMA (same quantized P as PV) ---
      f32x4 ls = {};
      ls = __builtin_amdgcn_mfma_f32_16x16x32_bf16(ones, pf0, ls, 0,0,0);
      ls = __builtin_amdgcn_mfma_f32_16x16x32_bf16(ones, pf1, ls, 0,0,0);
      l_q = l_q*sc + ls[0];
      if (__any(sc != 1.0f)){
        #pragma unroll
        for (int dt=0;dt<8;++dt)
          #pragma unroll
          for (int r=0;r<4;++r) accO[dt][r] *= sc;
      }
      // --- PV: O^T += V^T @ P^T (V from LDS) ---
      const u16* Vsc = &Vs[cur][0];
      const int cb0 = (g*16) ^ sw;
      const int cb1 = (64 + g*16) ^ sw;
      __builtin_amdgcn_s_setprio(1);
      #pragma unroll
      for (int dt=0;dt<8;++dt){
        s16x8 vf0 = *(const s16x8*)(Vsc + (dt*16+lr)*64 + (cb0>>1));
        accO[dt] = __builtin_amdgcn_mfma_f32_16x16x32_bf16(vf0, pf0, accO[dt], 0,0,0);
        s16x8 vf1 = *(const s16x8*)(Vsc + (dt*16+lr)*64 + (cb1>>1));
        accO[dt] = __builtin_amdgcn_mfma_f32_16x16x32_bf16(vf1, pf1, accO[dt], 0,0,0);
      }
      __builtin_amdgcn_s_setprio(0);
      __syncthreads();          // staged t+1 visible; buffers swappable
      __builtin_amdgcn_sched_barrier(0);   // pin next-iter staging below barrier
      cur ^= 1;
    }
    // --- epilogue: transpose via LDS (aliases dead K staging), store ---
    const float linv = 1.0f / l_q;
    #pragma unroll
    for (int dt=0;dt<8;++dt)
      #pragma unroll
      for (int r=0;r<4;++r)
        Ol[w][lr][dt*16 + 4*g + r] = f2b(accO[dt][r] * linv);
    __syncthreads();
    #pragma unroll
    for (int p=0;p<4;++p){
      const int ql = p*4 + g;
      s16x8 ov = *(const s16x8*)(&Ol[w][ql][0] + lr*8);
      *(s16x8*)(Ob + (size_t)(q0+ql)*D_ + h*DK_ + lr*8) = ov;
    }
    __syncthreads();            // Ol reads done before next phase's STAGE_K
    __builtin_amdgcn_sched_barrier(0);
  }
  #undef STAGE_K
  #undef STAGE_V
}

// ---------------------------------------------------------------------------
extern "C" void kernel_launch(void* const* d_in, const int* in_sizes, int n_in,
                              void* d_out, int out_size, void* d_ws, size_t ws_size,
                              hipStream_t stream)
{
  const void* q   = d_in[0];
  const void* k   = d_in[1];
  const void* v   = d_in[2];
  const void* wq  = d_in[3];  const void* bq = d_in[4];
  const void* laq = d_in[5];  const void* lbq= d_in[6];
  const void* wk  = d_in[7];  const void* bk = d_in[8];
  const void* lak = d_in[9];  const void* lbk= d_in[10];
  const void* wv  = d_in[11]; const void* bv = d_in[12];
  const void* lav = d_in[13]; const void* lbv= d_in[14];
  const void* wo  = d_in[15]; const void* bo = d_in[16];
  const void* lao = d_in[17]; const void* lbo= d_in[18];

  char* ws = (char*)d_ws;
  int* flag = (int*)ws;
  char* base = ws + 256;
  const size_t MB = 1u<<20;
  u16* W   = (u16*)(base);            //  8 MiB, reused for each effW^T
  u16* Qb  = (u16*)(base +  8*MB);    // 16 MiB
  u16* Kb  = (u16*)(base + 24*MB);    // 16 MiB
  u16* Vb  = (u16*)(base + 40*MB);    // 16 MiB
  u16* VTb = (u16*)(base + 56*MB);    // 16 MiB
  u16* Ob  = Vb;                      // V dead after transpose
  u16* X   = (u16*)(base + 72*MB);    // 16 MiB, converted A (reused Q->K->V)
  const bool useCvt = ws_size >= (size_t)(88*MB + 256);

  dim3 blk(256);
  dim3 gW(D_/64, D_/64);
  dim3 gG(D_/128, MROWS/128);
  const int nElems = MROWS * D_;      // 8M elements per activation
  detect32<<<1, blk, 0, stream>>>((const unsigned*)q, flag);
  prep_wt<<<gW, blk, 0, stream>>>(wq, laq, lbq, W, flag);
  if (useCvt){
    cvt_bf16<<<2048, blk, 0, stream>>>(q, X, flag, nElems);
    gemm_bt<<<gG, blk, 0, stream>>>(X, W, bq, Qb, flag, 0, 0);
  } else {
    gemm_bt<<<gG, blk, 0, stream>>>(q, W, bq, Qb, flag, 1, 0);
  }
  prep_wt<<<gW, blk, 0, stream>>>(wk, lak, lbk, W, flag);
  if (useCvt){
    cvt_bf16<<<2048, blk, 0, stream>>>(k, X, flag, nElems);
    gemm_bt<<<gG, blk, 0, stream>>>(X, W, bk, Kb, flag, 0, 0);
  } else {
    gemm_bt<<<gG, blk, 0, stream>>>(k, W, bk, Kb, flag, 1, 0);
  }
  prep_wt<<<gW, blk, 0, stream>>>(wv, lav, lbv, W, flag);
  if (useCvt){
    cvt_bf16<<<2048, blk, 0, stream>>>(v, X, flag, nElems);
    gemm_bt<<<gG, blk, 0, stream>>>(X, W, bv, Vb, flag, 0, 0);
  } else {
    gemm_bt<<<gG, blk, 0, stream>>>(v, W, bv, Vb, flag, 1, 0);
  }
  transpose_v<<<dim3(S_/64, D_/64, B_), blk, 0, stream>>>(Vb, VTb);
  attn<<<dim3(S_/128, H_, B_), blk, 0, stream>>>(Qb, Kb, VTb, Ob);
  prep_wt<<<gW, blk, 0, stream>>>(wo, lao, lbo, W, flag);
  gemm_bt<<<gG, blk, 0, stream>>>(Ob, W, bo, d_out, flag, 0, 1);
}

// Round 19
// 326.549 us; speedup vs baseline: 1.3431x; 1.0184x over previous
//
#include <hip/hip_runtime.h>

// LoRA multi-head attention forward, B=2 S=2048 D=2048 H=16 dk=128 rank=8.
// Device dtype auto-detected (bf16 vs fp32) -> flag in ws; internal compute bf16.
// Pipeline: detect -> [cvt A -> prep effW^T -> GEMM] x3 (Q,K,V) -> V transpose
// -> causal flash attention -> prep effWo^T -> output GEMM.
// R19: prep_wt vectorized (f32x4/s16x4 loads, s16x8 stores; same math order ->
// bit-identical); attn softmax in exp2 domain (log2e folded into Q scale,
// native v_exp) + defer-max THR=8*log2e restored (race fixed in R16; defer is
// deterministic).  GEMM/attn structure otherwise identical to R18.

#define B_   2
#define S_   2048
#define D_   2048
#define H_   16
#define DK_  128
#define MROWS (B_*S_)            // 4096
#define SCALE2_ 0.1275174480491784f   // (1/sqrt(128)) * log2(e)
#define DEFER_THR_ 11.541560327f      // 8 * log2(e)

using f32x4 = __attribute__((ext_vector_type(4))) float;
using s16x8 = __attribute__((ext_vector_type(8))) short;
using s16x4 = __attribute__((ext_vector_type(4))) short;
typedef unsigned short u16;
typedef unsigned int u32;

__device__ __forceinline__ float b2f(u16 u){ union{unsigned u32v; float f;} x; x.u32v=((unsigned)u)<<16; return x.f; }
__device__ __forceinline__ u16 f2b(float f){ union{float f; unsigned u;} x; x.f=f; unsigned r=x.u+0x7fffu+((x.u>>16)&1u); return (u16)(r>>16); }
__device__ __forceinline__ u32 pk2(float lo, float hi){
  return ((u32)f2b(hi) << 16) | (u32)f2b(lo);
}

__device__ __forceinline__ void glds16(const void* g, void* l){
  __builtin_amdgcn_global_load_lds((const __attribute__((address_space(1))) unsigned int*)g,
                                   (__attribute__((address_space(3))) unsigned int*)l, 16, 0, 0);
}

// ---------------------------------------------------------------------------
__global__ void detect32(const unsigned* __restrict__ q, int* __restrict__ flag)
{
  __shared__ int s[4];
  int c = 0;
  for (int i = threadIdx.x; i < 4096; i += 256){
    unsigned u = q[i];
    unsigned e0 = (u >> 7) & 0xFFu;
    if (e0 >= 0x90u) ++c;
  }
  #pragma unroll
  for (int off = 32; off; off >>= 1) c += __shfl_down(c, off);
  if ((threadIdx.x & 63) == 0) s[threadIdx.x >> 6] = c;
  __syncthreads();
  if (threadIdx.x == 0) *flag = ((s[0]+s[1]+s[2]+s[3]) > 64) ? 1 : 0;
}

// ---------------------------------------------------------------------------
// A-operand conversion: fp32 -> bf16 (same f2b as before) or straight copy.
__global__ __launch_bounds__(256) void cvt_bf16(const void* __restrict__ src, u16* __restrict__ dst,
                                                const int* __restrict__ flagp, int n)
{
  const int f = *flagp;
  const int n8 = n >> 3;
  const int stride = gridDim.x * blockDim.x;
  if (f){
    const f32x4* s = (const f32x4*)src;
    for (int j = blockIdx.x*blockDim.x + threadIdx.x; j < n8; j += stride){
      f32x4 a = s[2*j], b = s[2*j+1];
      s16x8 o;
      #pragma unroll
      for (int r=0;r<4;++r){ o[r] = (short)f2b(a[r]); o[4+r] = (short)f2b(b[r]); }
      ((s16x8*)dst)[j] = o;
    }
  } else {
    const s16x8* s = (const s16x8*)src;
    for (int j = blockIdx.x*blockDim.x + threadIdx.x; j < n8; j += stride)
      ((s16x8*)dst)[j] = s[j];
  }
}

// ---------------------------------------------------------------------------
// effWT[n][k] = w[k][n] + sum_r la[k][r]*lb[r][n]   (vectorized, R19)
// Phase1: thread (tid) computes rows r4..r4+3 x cols c4..c4+3 into LDS.
// Phase2: thread writes wt row n0+(tid>>2), k-chunk (tid&3)*16 (2x s16x8).
__global__ __launch_bounds__(256) void prep_wt(const void* __restrict__ w_, const void* __restrict__ la_,
                                               const void* __restrict__ lb_, u16* __restrict__ wt,
                                               const int* __restrict__ flagp)
{
  const int f32i = *flagp;
  __shared__ float tile[64][68];       // [k][n], padded
  const int tid = threadIdx.x;
  const int k0 = blockIdx.x*64, n0 = blockIdx.y*64;
  const int c4 = (tid & 15)*4;         // 4 n-cols
  const int r4 = (tid >> 4)*4;         // 4 k-rows
  float lbv[8][4];
  if (f32i){
    const float* lb = (const float*)lb_;
    #pragma unroll
    for (int r=0;r<8;++r){
      f32x4 v = *(const f32x4*)(lb + (size_t)r*D_ + n0 + c4);
      #pragma unroll
      for (int j=0;j<4;++j) lbv[r][j] = v[j];
    }
    const float* w32 = (const float*)w_;  const float* la = (const float*)la_;
    #pragma unroll
    for (int i=0;i<4;++i){
      const int k = k0 + r4 + i;
      f32x4 wv = *(const f32x4*)(w32 + (size_t)k*D_ + n0 + c4);
      f32x4 a0 = *(const f32x4*)(la + k*8);
      f32x4 a1 = *(const f32x4*)(la + k*8 + 4);
      float val[4];
      #pragma unroll
      for (int j=0;j<4;++j) val[j] = wv[j];
      #pragma unroll
      for (int r=0;r<4;++r)
        #pragma unroll
        for (int j=0;j<4;++j) val[j] += a0[r]*lbv[r][j];
      #pragma unroll
      for (int r=0;r<4;++r)
        #pragma unroll
        for (int j=0;j<4;++j) val[j] += a1[r]*lbv[4+r][j];
      #pragma unroll
      for (int j=0;j<4;++j) tile[r4+i][c4+j] = val[j];
    }
  } else {
    const u16* lb = (const u16*)lb_;
    #pragma unroll
    for (int r=0;r<8;++r){
      s16x4 v = *(const s16x4*)(lb + (size_t)r*D_ + n0 + c4);
      #pragma unroll
      for (int j=0;j<4;++j) lbv[r][j] = b2f((u16)v[j]);
    }
    const u16* w16 = (const u16*)w_;  const u16* la = (const u16*)la_;
    #pragma unroll
    for (int i=0;i<4;++i){
      const int k = k0 + r4 + i;
      s16x4 wv = *(const s16x4*)(w16 + (size_t)k*D_ + n0 + c4);
      s16x8 av = *(const s16x8*)(la + k*8);
      float val[4];
      #pragma unroll
      for (int j=0;j<4;++j) val[j] = b2f((u16)wv[j]);
      #pragma unroll
      for (int r=0;r<8;++r){
        const float ar = b2f((u16)av[r]);
        #pragma unroll
        for (int j=0;j<4;++j) val[j] += ar*lbv[r][j];
      }
      #pragma unroll
      for (int j=0;j<4;++j) tile[r4+i][c4+j] = val[j];
    }
  }
  __syncthreads();
  const int nr = tid >> 2;             // 0..63
  const int kc = (tid & 3) * 16;       // 0,16,32,48
  s16x8 o0, o1;
  #pragma unroll
  for (int j=0;j<8;++j){
    o0[j] = (short)f2b(tile[kc+j][nr]);
    o1[j] = (short)f2b(tile[kc+8+j][nr]);
  }
  *(s16x8*)(wt + (size_t)(n0+nr)*D_ + k0 + kc)     = o0;
  *(s16x8*)(wt + (size_t)(n0+nr)*D_ + k0 + kc + 8) = o1;
}

// ---------------------------------------------------------------------------
__global__ __launch_bounds__(256) void transpose_v(const u16* __restrict__ V, u16* __restrict__ VT)
{
  __shared__ u16 tile[64][66];
  const int bz = blockIdx.z;
  const int s0 = blockIdx.x*64, d0 = blockIdx.y*64;
  const int tid = threadIdx.x;
  const u16* Vb = V + (size_t)bz*S_*D_;
  u16* VTb = VT + (size_t)bz*D_*S_;
  const int c = tid & 63, r0 = (tid>>6)*16;
  #pragma unroll
  for (int i=0;i<16;++i) tile[r0+i][c] = Vb[(size_t)(s0+r0+i)*D_ + d0 + c];
  __syncthreads();
  #pragma unroll
  for (int i=0;i<16;++i) VTb[(size_t)(d0+r0+i)*S_ + s0 + c] = tile[c][r0+i];
}

// ---------------------------------------------------------------------------
// C[m][n] = sum_k A[m][k]*BT[n][k] + bias[n].  M=4096, N=K=2048.
// 128x128 tile, BK=64, double-buffered prefetch, one barrier/iter.
// T1 chunked XCD swizzle (512%8==0, bijective).
// Swizzle invariant: LDS[row][c] = global[row][c ^ ((row&7)<<3)] (u16 units).
__global__ __launch_bounds__(256) void gemm_bt(const void* __restrict__ A_, const u16* __restrict__ BT,
                                               const void* __restrict__ bias_, void* __restrict__ C_,
                                               const int* __restrict__ flagp, int aF, int oF)
{
  constexpr int N = D_, K = D_;
  constexpr int NT = K/64;
  const int f = *flagp;
  const bool a32 = (aF != 0) && (f != 0);
  const bool o32 = (oF != 0) && (f != 0);
  __shared__ u16 As[2][128*64];      // 32 KB
  __shared__ u16 Bs[2][128*64];      // 32 KB
  const int tid = threadIdx.x;
  const int w = tid>>6, lane = tid&63, g = lane>>4, lr = lane&15;
  const int wm = w>>1, wn = w&1;
  // T1 XCD swizzle (requires nwg % 8 == 0; here 16*32=512)
  const unsigned flat = blockIdx.y*gridDim.x + blockIdx.x;
  const unsigned cpx  = (gridDim.x*gridDim.y) >> 3;        // 64
  const unsigned swz  = (flat & 7)*cpx + (flat >> 3);
  const int m0 = (int)(swz / gridDim.x) * 128;
  const int n0 = (int)(swz % gridDim.x) * 128;
  const int srow = lane>>3;                        // 0..7
  const int lcol = (lane&7)*8;                     // linear col, u16 units
  const int scol = lcol ^ (srow<<3);               // swizzled col
  const int rsw  = (lr&7)<<3;                      // read-side swizzle (u16)

  const float* Af = (const float*)A_;
  const u16*   Ab = (const u16*)A_;

  #define STAGE_B16(buf, k0_) do{ _Pragma("unroll")                                 \
    for (int jj=0;jj<4;++jj){ const int rb = w*32 + jj*8;                           \
      glds16(BT + (size_t)(n0+rb+srow)*K + (k0_) + scol, (void*)(&Bs[buf][0] + rb*64)); } }while(0)
  #define STAGE_A16(buf, k0_) do{ _Pragma("unroll")                                 \
    for (int jj=0;jj<4;++jj){ const int rb = w*32 + jj*8;                           \
      glds16(Ab + (size_t)(m0+rb+srow)*K + (k0_) + scol, (void*)(&As[buf][0] + rb*64)); } }while(0)
  #define LOAD_A32(k0_) do{ _Pragma("unroll")                                       \
    for (int jj=0;jj<4;++jj){                                                       \
      const float* src = Af + (size_t)(m0 + w*32 + jj*8 + srow)*K + (k0_) + lcol;   \
      ax0[jj] = *(const f32x4*)src; ax1[jj] = *(const f32x4*)(src + 4); } }while(0)
  #define WRITE_A32(buf) do{ _Pragma("unroll")                                      \
    for (int jj=0;jj<4;++jj){ const int rb = w*32 + jj*8; s16x8 pk;                 \
      _Pragma("unroll")                                                             \
      for (int i=0;i<4;++i){ pk[i]=(short)f2b(ax0[jj][i]); pk[4+i]=(short)f2b(ax1[jj][i]); } \
      *(s16x8*)(&As[buf][0] + (rb+srow)*64 + scol) = pk; } }while(0)

  f32x4 ax0[4], ax1[4];
  f32x4 acc[4][4] = {};

  if (a32){ LOAD_A32(0); WRITE_A32(0); } else { STAGE_A16(0, 0); }
  STAGE_B16(0, 0);
  __syncthreads();
  __builtin_amdgcn_sched_barrier(0);

  int cur = 0;
  for (int t=0; t<NT; ++t){
    const bool haveNext = (t+1 < NT);
    if (haveNext){
      if (a32) LOAD_A32((t+1)*64);              // issue early; write after compute
      else     STAGE_A16(cur^1, (t+1)*64);
      STAGE_B16(cur^1, (t+1)*64);
    }
    #pragma unroll
    for (int kk=0;kk<2;++kk){
      s16x8 af[4], bfr[4];
      #pragma unroll
      for (int i=0;i<4;++i) af[i]  = *(const s16x8*)(&As[cur][0] + (wm*64+i*16+lr)*64 + ((kk*32 + g*8) ^ rsw));
      #pragma unroll
      for (int i=0;i<4;++i) bfr[i] = *(const s16x8*)(&Bs[cur][0] + (wn*64+i*16+lr)*64 + ((kk*32 + g*8) ^ rsw));
      #pragma unroll
      for (int mi=0;mi<4;++mi)
        #pragma unroll
        for (int ni=0;ni<4;++ni)
          acc[mi][ni] = __builtin_amdgcn_mfma_f32_16x16x32_bf16(af[mi], bfr[ni], acc[mi][ni], 0,0,0);
    }
    if (haveNext && a32) WRITE_A32(cur^1);      // vmcnt wait lands after MFMAs
    __syncthreads();
    __builtin_amdgcn_sched_barrier(0);          // pin next-iter staging below barrier
    cur ^= 1;
  }
  #pragma unroll
  for (int ni=0;ni<4;++ni){
    const int n = n0 + wn*64 + ni*16 + lr;
    const float bv = f ? ((const float*)bias_)[n] : b2f(((const u16*)bias_)[n]);
    #pragma unroll
    for (int mi=0;mi<4;++mi){
      const int m = m0 + wm*64 + mi*16 + 4*g;
      #pragma unroll
      for (int r=0;r<4;++r){
        const float val = acc[mi][ni][r] + bv;
        if (o32) ((float*)C_)[(size_t)(m+r)*N + n] = val;
        else     ((u16*)C_)[(size_t)(m+r)*N + n] = f2b(val);
      }
    }
  }
  #undef STAGE_B16
  #undef STAGE_A16
  #undef LOAD_A32
  #undef WRITE_A32
}

// ---------------------------------------------------------------------------
// Causal flash attention.  grid (S/128, H, B), block 256 (4 waves x 16 q-rows).
// PAIRED blocks: work x handles q-tiles x and 31-x; XCD-chunked remap (64
// consecutive works = 4 complete (h,bz) groups per XCD).  K,V staged in LDS
// (dbuf, XOR swizzle, 1 barrier/tile + sched_barrier pin).  Swapped QK^T,
// lane-local softmax in exp2 domain (q=lr), defer-max THR=8*log2e, f2b pack
// + 16-shfl gather, ones-MFMA l-sum.
__global__ __launch_bounds__(256) void attn(const u16* __restrict__ Q, const u16* __restrict__ K,
                                            const u16* __restrict__ VT, u16* __restrict__ O)
{
  __shared__ u16  Ks[2][64*128];     // 32 KB, rows kv (256B), swizzled
  __shared__ u16  Vs[2][128*64];     // 32 KB, rows d (128B), swizzled
  u16 (*Ol)[16][136] = (u16(*)[16][136])(&Ks[0][0]);   // epilogue alias, dead staging

  const int tid = threadIdx.x;
  const int w = tid>>6, lane = tid&63, g = lane>>4, lr = lane&15;
  // XCD-chunked work remap (T1): rr-dispatch flat -> 64-chunk per XCD
  const unsigned flat = blockIdx.x + gridDim.x*(blockIdx.y + gridDim.y*blockIdx.z);
  const unsigned work = (flat & 7)*64u + (flat >> 3);   // bijective on [0,512)
  const int xp = (int)(work & 15);          // pair index 0..15
  const int h  = (int)((work >> 4) & 15);   // head
  const int bz = (int)(work >> 8);          // batch
  const u16* Qb  = Q  + (size_t)bz*S_*D_;
  const u16* Kb  = K  + (size_t)bz*S_*D_;
  const u16* VTb = VT + (size_t)bz*D_*S_;
  u16* Ob = O + (size_t)bz*S_*D_;
  const int sw = (lr&7)<<4;                 // read-side swizzle (bytes)
  const int krow_l = lane>>4, kcol_l = (lane&15)*16;   // K staging lane map
  const int vrow_l = lane>>3, vcol_l = (lane&7)*16;    // V staging lane map

  s16x8 ones;
  #pragma unroll
  for (int i=0;i<8;++i) ones[i] = (short)0x3F80;       // bf16 1.0

  #define STAGE_K(buf, t_) do{ const int kv0s = (t_)*64;                            \
    _Pragma("unroll")                                                               \
    for (int jj=0;jj<4;++jj){ const int j = w*4 + jj; const int r = j*4 + krow_l;   \
      const int cb = kcol_l ^ ((r&7)<<4);                                           \
      glds16(Kb + (size_t)(kv0s + r)*D_ + h*DK_ + (cb>>1), (void*)(&Ks[buf][0] + j*512)); } }while(0)
  #define STAGE_V(buf, t_) do{ const int kv0s = (t_)*64;                            \
    _Pragma("unroll")                                                               \
    for (int jj=0;jj<4;++jj){ const int j = w*4 + jj; const int r = j*8 + vrow_l;   \
      const int cb = vcol_l ^ ((r&7)<<4);                                           \
      glds16(VTb + (size_t)(h*DK_ + r)*S_ + kv0s + (cb>>1), (void*)(&Vs[buf][0] + j*512)); } }while(0)

  for (int qq=0; qq<2; ++qq){
    const int qt = qq ? (int)(S_/64 - 1 - xp) : xp;
    const int q0 = qt*64 + w*16;
    const int nt = qt + 1;

    // Q fragments, pre-scaled by log2e/sqrt(dk) (exp2-domain softmax)
    s16x8 qf[4];
    #pragma unroll
    for (int dc=0;dc<4;++dc){
      s16x8 t = *(const s16x8*)(Qb + (size_t)(q0+lr)*D_ + h*DK_ + dc*32 + g*8);
      #pragma unroll
      for (int i=0;i<8;++i) t[i] = (short)f2b(b2f((u16)t[i]) * SCALE2_);
      qf[dc] = t;
    }
    float m_  = -1e30f;              // running max (log2 units), lane-local
    float l_q = 0.f;                 // row-sum for q-row lr (lane-local)
    f32x4 accO[8] = {};              // O^T[d=dt*16+4g+r][q=lr], fp32

    STAGE_K(0, 0); STAGE_V(0, 0);
    __syncthreads();
    __builtin_amdgcn_sched_barrier(0);
    int cur = 0;
    for (int t=0;t<nt;++t){
      const int kv0 = t*64;
      const bool lastT = (t == nt-1);
      if (!lastT){ STAGE_K(cur^1, t+1); STAGE_V(cur^1, t+1); }
      // --- QK^T (swapped): sacc[kt][r] = S[q=lr][key=kt*16+4g+r] ---
      const u16* Ksc = &Ks[cur][0];
      f32x4 sacc[4] = {};
      __builtin_amdgcn_s_setprio(1);
      #pragma unroll
      for (int dc=0;dc<4;++dc){
        const int cb = (dc*64 + g*16) ^ sw;
        #pragma unroll
        for (int kt=0;kt<4;++kt){
          s16x8 kf = *(const s16x8*)(Ksc + (kt*16+lr)*128 + (cb>>1));
          sacc[kt] = __builtin_amdgcn_mfma_f32_16x16x32_bf16(kf, qf[dc], sacc[kt], 0,0,0);
        }
      }
      __builtin_amdgcn_s_setprio(0);
      if (lastT){
        #pragma unroll
        for (int kt=0;kt<4;++kt)
          #pragma unroll
          for (int r=0;r<4;++r)
            if (kv0 + kt*16 + 4*g + r > q0 + lr) sacc[kt][r] = -1e30f;
      }
      // --- lane-local online softmax (q=lr), exp2 domain, defer-max ---
      float tm = sacc[0][0];
      #pragma unroll
      for (int kt=0;kt<4;++kt)
        #pragma unroll
        for (int r=0;r<4;++r) tm = fmaxf(tm, sacc[kt][r]);
      tm = fmaxf(tm, __shfl_xor(tm, 16));
      tm = fmaxf(tm, __shfl_xor(tm, 32));
      const float mn = (tm <= m_ + DEFER_THR_) ? m_ : tm;  // defer small growth
      const float sc = exp2f(m_ - mn);                     // ==1 when deferred
      m_ = mn;
      #pragma unroll
      for (int kt=0;kt<4;++kt)
        #pragma unroll
        for (int r=0;r<4;++r) sacc[kt][r] = exp2f(sacc[kt][r] - mn);
      // --- pack P to bf16 pairs (f2b) and gather B-operand fragments ---
      u32 pa[4], pb[4];
      #pragma unroll
      for (int kt=0;kt<4;++kt){
        pa[kt] = pk2(sacc[kt][0], sacc[kt][1]);
        pb[kt] = pk2(sacc[kt][2], sacc[kt][3]);
      }
      const int srcA = lr + 32*(g&1);
      const int srcB = srcA + 16;
      const bool hi = (g >= 2);
      union { s16x8 v; u32 u[4]; } P0, P1;
      {
        u32 a0 = (u32)__shfl((int)pa[0], srcA), a1 = (u32)__shfl((int)pa[1], srcA);
        u32 b0 = (u32)__shfl((int)pb[0], srcA), b1 = (u32)__shfl((int)pb[1], srcA);
        u32 c0 = (u32)__shfl((int)pa[0], srcB), c1 = (u32)__shfl((int)pa[1], srcB);
        u32 d0 = (u32)__shfl((int)pb[0], srcB), d1 = (u32)__shfl((int)pb[1], srcB);
        P0.u[0] = hi ? a1 : a0;  P0.u[1] = hi ? b1 : b0;
        P0.u[2] = hi ? c1 : c0;  P0.u[3] = hi ? d1 : d0;
      }
      {
        u32 a0 = (u32)__shfl((int)pa[2], srcA), a1 = (u32)__shfl((int)pa[3], srcA);
        u32 b0 = (u32)__shfl((int)pb[2], srcA), b1 = (u32)__shfl((int)pb[3], srcA);
        u32 c0 = (u32)__shfl((int)pa[2], srcB), c1 = (u32)__shfl((int)pa[3], srcB);
        u32 d0 = (u32)__shfl((int)pb[2], srcB), d1 = (u32)__shfl((int)pb[3], srcB);
        P1.u[0] = hi ? a1 : a0;  P1.u[1] = hi ? b1 : b0;
        P1.u[2] = hi ? c1 : c0;  P1.u[3] = hi ? d1 : d0;
      }
      const s16x8 pf0 = P0.v, pf1 = P1.v;
      // --- l-sum via ones-MFMA (same quantized P as PV) ---
      f32x4 ls = {};
      ls = __builtin_amdgcn_mfma_f32_16x16x32_bf16(ones, pf0, ls, 0,0,0);
      ls = __builtin_amdgcn_mfma_f32_16x16x32_bf16(ones, pf1, ls, 0,0,0);
      l_q = l_q*sc + ls[0];
      if (__any(sc != 1.0f)){
        #pragma unroll
        for (int dt=0;dt<8;++dt)
          #pragma unroll
          for (int r=0;r<4;++r) accO[dt][r] *= sc;
      }
      // --- PV: O^T += V^T @ P^T (V from LDS) ---
      const u16* Vsc = &Vs[cur][0];
      const int cb0 = (g*16) ^ sw;
      const int cb1 = (64 + g*16) ^ sw;
      __builtin_amdgcn_s_setprio(1);
      #pragma unroll
      for (int dt=0;dt<8;++dt){
        s16x8 vf0 = *(const s16x8*)(Vsc + (dt*16+lr)*64 + (cb0>>1));
        accO[dt] = __builtin_amdgcn_mfma_f32_16x16x32_bf16(vf0, pf0, accO[dt], 0,0,0);
        s16x8 vf1 = *(const s16x8*)(Vsc + (dt*16+lr)*64 + (cb1>>1));
        accO[dt] = __builtin_amdgcn_mfma_f32_16x16x32_bf16(vf1, pf1, accO[dt], 0,0,0);
      }
      __builtin_amdgcn_s_setprio(0);
      __syncthreads();          // staged t+1 visible; buffers swappable
      __builtin_amdgcn_sched_barrier(0);   // pin next-iter staging below barrier
      cur ^= 1;
    }
    // --- epilogue: transpose via LDS (aliases dead K staging), store ---
    const float linv = 1.0f / l_q;
    #pragma unroll
    for (int dt=0;dt<8;++dt)
      #pragma unroll
      for (int r=0;r<4;++r)
        Ol[w][lr][dt*16 + 4*g + r] = f2b(accO[dt][r] * linv);
    __syncthreads();
    #pragma unroll
    for (int p=0;p<4;++p){
      const int ql = p*4 + g;
      s16x8 ov = *(const s16x8*)(&Ol[w][ql][0] + lr*8);
      *(s16x8*)(Ob + (size_t)(q0+ql)*D_ + h*DK_ + lr*8) = ov;
    }
    __syncthreads();            // Ol reads done before next phase's STAGE_K
    __builtin_amdgcn_sched_barrier(0);
  }
  #undef STAGE_K
  #undef STAGE_V
}

// ---------------------------------------------------------------------------
extern "C" void kernel_launch(void* const* d_in, const int* in_sizes, int n_in,
                              void* d_out, int out_size, void* d_ws, size_t ws_size,
                              hipStream_t stream)
{
  const void* q   = d_in[0];
  const void* k   = d_in[1];
  const void* v   = d_in[2];
  const void* wq  = d_in[3];  const void* bq = d_in[4];
  const void* laq = d_in[5];  const void* lbq= d_in[6];
  const void* wk  = d_in[7];  const void* bk = d_in[8];
  const void* lak = d_in[9];  const void* lbk= d_in[10];
  const void* wv  = d_in[11]; const void* bv = d_in[12];
  const void* lav = d_in[13]; const void* lbv= d_in[14];
  const void* wo  = d_in[15]; const void* bo = d_in[16];
  const void* lao = d_in[17]; const void* lbo= d_in[18];

  char* ws = (char*)d_ws;
  int* flag = (int*)ws;
  char* base = ws + 256;
  const size_t MB = 1u<<20;
  u16* W   = (u16*)(base);            //  8 MiB, reused for each effW^T
  u16* Qb  = (u16*)(base +  8*MB);    // 16 MiB
  u16* Kb  = (u16*)(base + 24*MB);    // 16 MiB
  u16* Vb  = (u16*)(base + 40*MB);    // 16 MiB
  u16* VTb = (u16*)(base + 56*MB);    // 16 MiB
  u16* Ob  = Vb;                      // V dead after transpose
  u16* X   = (u16*)(base + 72*MB);    // 16 MiB, converted A (reused Q->K->V)
  const bool useCvt = ws_size >= (size_t)(88*MB + 256);

  dim3 blk(256);
  dim3 gW(D_/64, D_/64);
  dim3 gG(D_/128, MROWS/128);
  const int nElems = MROWS * D_;      // 8M elements per activation
  detect32<<<1, blk, 0, stream>>>((const unsigned*)q, flag);
  prep_wt<<<gW, blk, 0, stream>>>(wq, laq, lbq, W, flag);
  if (useCvt){
    cvt_bf16<<<2048, blk, 0, stream>>>(q, X, flag, nElems);
    gemm_bt<<<gG, blk, 0, stream>>>(X, W, bq, Qb, flag, 0, 0);
  } else {
    gemm_bt<<<gG, blk, 0, stream>>>(q, W, bq, Qb, flag, 1, 0);
  }
  prep_wt<<<gW, blk, 0, stream>>>(wk, lak, lbk, W, flag);
  if (useCvt){
    cvt_bf16<<<2048, blk, 0, stream>>>(k, X, flag, nElems);
    gemm_bt<<<gG, blk, 0, stream>>>(X, W, bk, Kb, flag, 0, 0);
  } else {
    gemm_bt<<<gG, blk, 0, stream>>>(k, W, bk, Kb, flag, 1, 0);
  }
  prep_wt<<<gW, blk, 0, stream>>>(wv, lav, lbv, W, flag);
  if (useCvt){
    cvt_bf16<<<2048, blk, 0, stream>>>(v, X, flag, nElems);
    gemm_bt<<<gG, blk, 0, stream>>>(X, W, bv, Vb, flag, 0, 0);
  } else {
    gemm_bt<<<gG, blk, 0, stream>>>(v, W, bv, Vb, flag, 1, 0);
  }
  transpose_v<<<dim3(S_/64, D_/64, B_), blk, 0, stream>>>(Vb, VTb);
  attn<<<dim3(S_/128, H_, B_), blk, 0, stream>>>(Qb, Kb, VTb, Ob);
  prep_wt<<<gW, blk, 0, stream>>>(wo, lao, lbo, W, flag);
  gemm_bt<<<gG, blk, 0, stream>>>(Ob, W, bo, d_out, flag, 0, 1);
}

// Round 20
// 315.109 us; speedup vs baseline: 1.3919x; 1.0363x over previous
//
#include <hip/hip_runtime.h>

// LoRA multi-head attention forward, B=2 S=2048 D=2048 H=16 dk=128 rank=8.
// Device dtype auto-detected (bf16 vs fp32) -> flag in ws; internal compute bf16.
// Pipeline: detect -> [cvt A -> prep effW^T -> GEMM] x3 (Q,K,V) -> V transpose
// -> causal flash attention -> prep effWo^T -> output GEMM.
// R20: attn reverted to R18 exactly (expf + FULL max; R19's exp2+defer-max
// regressed attn 86->91us and absmax 0.016->0.060).  Keeps R19's vectorized
// prep_wt (bit-identical, ~12us).  GEMM/cvt/remaps unchanged.

#define B_   2
#define S_   2048
#define D_   2048
#define H_   16
#define DK_  128
#define MROWS (B_*S_)            // 4096
#define SCALE_ 0.08838834764831845f   // 1/sqrt(128)

using f32x4 = __attribute__((ext_vector_type(4))) float;
using s16x8 = __attribute__((ext_vector_type(8))) short;
using s16x4 = __attribute__((ext_vector_type(4))) short;
typedef unsigned short u16;
typedef unsigned int u32;

__device__ __forceinline__ float b2f(u16 u){ union{unsigned u32v; float f;} x; x.u32v=((unsigned)u)<<16; return x.f; }
__device__ __forceinline__ u16 f2b(float f){ union{float f; unsigned u;} x; x.f=f; unsigned r=x.u+0x7fffu+((x.u>>16)&1u); return (u16)(r>>16); }
__device__ __forceinline__ u32 pk2(float lo, float hi){
  return ((u32)f2b(hi) << 16) | (u32)f2b(lo);
}

__device__ __forceinline__ void glds16(const void* g, void* l){
  __builtin_amdgcn_global_load_lds((const __attribute__((address_space(1))) unsigned int*)g,
                                   (__attribute__((address_space(3))) unsigned int*)l, 16, 0, 0);
}

// ---------------------------------------------------------------------------
__global__ void detect32(const unsigned* __restrict__ q, int* __restrict__ flag)
{
  __shared__ int s[4];
  int c = 0;
  for (int i = threadIdx.x; i < 4096; i += 256){
    unsigned u = q[i];
    unsigned e0 = (u >> 7) & 0xFFu;
    if (e0 >= 0x90u) ++c;
  }
  #pragma unroll
  for (int off = 32; off; off >>= 1) c += __shfl_down(c, off);
  if ((threadIdx.x & 63) == 0) s[threadIdx.x >> 6] = c;
  __syncthreads();
  if (threadIdx.x == 0) *flag = ((s[0]+s[1]+s[2]+s[3]) > 64) ? 1 : 0;
}

// ---------------------------------------------------------------------------
// A-operand conversion: fp32 -> bf16 (same f2b as before) or straight copy.
__global__ __launch_bounds__(256) void cvt_bf16(const void* __restrict__ src, u16* __restrict__ dst,
                                                const int* __restrict__ flagp, int n)
{
  const int f = *flagp;
  const int n8 = n >> 3;
  const int stride = gridDim.x * blockDim.x;
  if (f){
    const f32x4* s = (const f32x4*)src;
    for (int j = blockIdx.x*blockDim.x + threadIdx.x; j < n8; j += stride){
      f32x4 a = s[2*j], b = s[2*j+1];
      s16x8 o;
      #pragma unroll
      for (int r=0;r<4;++r){ o[r] = (short)f2b(a[r]); o[4+r] = (short)f2b(b[r]); }
      ((s16x8*)dst)[j] = o;
    }
  } else {
    const s16x8* s = (const s16x8*)src;
    for (int j = blockIdx.x*blockDim.x + threadIdx.x; j < n8; j += stride)
      ((s16x8*)dst)[j] = s[j];
  }
}

// ---------------------------------------------------------------------------
// effWT[n][k] = w[k][n] + sum_r la[k][r]*lb[r][n]   (vectorized, R19)
__global__ __launch_bounds__(256) void prep_wt(const void* __restrict__ w_, const void* __restrict__ la_,
                                               const void* __restrict__ lb_, u16* __restrict__ wt,
                                               const int* __restrict__ flagp)
{
  const int f32i = *flagp;
  __shared__ float tile[64][68];       // [k][n], padded
  const int tid = threadIdx.x;
  const int k0 = blockIdx.x*64, n0 = blockIdx.y*64;
  const int c4 = (tid & 15)*4;         // 4 n-cols
  const int r4 = (tid >> 4)*4;         // 4 k-rows
  float lbv[8][4];
  if (f32i){
    const float* lb = (const float*)lb_;
    #pragma unroll
    for (int r=0;r<8;++r){
      f32x4 v = *(const f32x4*)(lb + (size_t)r*D_ + n0 + c4);
      #pragma unroll
      for (int j=0;j<4;++j) lbv[r][j] = v[j];
    }
    const float* w32 = (const float*)w_;  const float* la = (const float*)la_;
    #pragma unroll
    for (int i=0;i<4;++i){
      const int k = k0 + r4 + i;
      f32x4 wv = *(const f32x4*)(w32 + (size_t)k*D_ + n0 + c4);
      f32x4 a0 = *(const f32x4*)(la + k*8);
      f32x4 a1 = *(const f32x4*)(la + k*8 + 4);
      float val[4];
      #pragma unroll
      for (int j=0;j<4;++j) val[j] = wv[j];
      #pragma unroll
      for (int r=0;r<4;++r)
        #pragma unroll
        for (int j=0;j<4;++j) val[j] += a0[r]*lbv[r][j];
      #pragma unroll
      for (int r=0;r<4;++r)
        #pragma unroll
        for (int j=0;j<4;++j) val[j] += a1[r]*lbv[4+r][j];
      #pragma unroll
      for (int j=0;j<4;++j) tile[r4+i][c4+j] = val[j];
    }
  } else {
    const u16* lb = (const u16*)lb_;
    #pragma unroll
    for (int r=0;r<8;++r){
      s16x4 v = *(const s16x4*)(lb + (size_t)r*D_ + n0 + c4);
      #pragma unroll
      for (int j=0;j<4;++j) lbv[r][j] = b2f((u16)v[j]);
    }
    const u16* w16 = (const u16*)w_;  const u16* la = (const u16*)la_;
    #pragma unroll
    for (int i=0;i<4;++i){
      const int k = k0 + r4 + i;
      s16x4 wv = *(const s16x4*)(w16 + (size_t)k*D_ + n0 + c4);
      s16x8 av = *(const s16x8*)(la + k*8);
      float val[4];
      #pragma unroll
      for (int j=0;j<4;++j) val[j] = b2f((u16)wv[j]);
      #pragma unroll
      for (int r=0;r<8;++r){
        const float ar = b2f((u16)av[r]);
        #pragma unroll
        for (int j=0;j<4;++j) val[j] += ar*lbv[r][j];
      }
      #pragma unroll
      for (int j=0;j<4;++j) tile[r4+i][c4+j] = val[j];
    }
  }
  __syncthreads();
  const int nr = tid >> 2;             // 0..63
  const int kc = (tid & 3) * 16;       // 0,16,32,48
  s16x8 o0, o1;
  #pragma unroll
  for (int j=0;j<8;++j){
    o0[j] = (short)f2b(tile[kc+j][nr]);
    o1[j] = (short)f2b(tile[kc+8+j][nr]);
  }
  *(s16x8*)(wt + (size_t)(n0+nr)*D_ + k0 + kc)     = o0;
  *(s16x8*)(wt + (size_t)(n0+nr)*D_ + k0 + kc + 8) = o1;
}

// ---------------------------------------------------------------------------
__global__ __launch_bounds__(256) void transpose_v(const u16* __restrict__ V, u16* __restrict__ VT)
{
  __shared__ u16 tile[64][66];
  const int bz = blockIdx.z;
  const int s0 = blockIdx.x*64, d0 = blockIdx.y*64;
  const int tid = threadIdx.x;
  const u16* Vb = V + (size_t)bz*S_*D_;
  u16* VTb = VT + (size_t)bz*D_*S_;
  const int c = tid & 63, r0 = (tid>>6)*16;
  #pragma unroll
  for (int i=0;i<16;++i) tile[r0+i][c] = Vb[(size_t)(s0+r0+i)*D_ + d0 + c];
  __syncthreads();
  #pragma unroll
  for (int i=0;i<16;++i) VTb[(size_t)(d0+r0+i)*S_ + s0 + c] = tile[c][r0+i];
}

// ---------------------------------------------------------------------------
// C[m][n] = sum_k A[m][k]*BT[n][k] + bias[n].  M=4096, N=K=2048.
// 128x128 tile, BK=64, double-buffered prefetch, one barrier/iter.
// T1 chunked XCD swizzle (512%8==0, bijective).
__global__ __launch_bounds__(256) void gemm_bt(const void* __restrict__ A_, const u16* __restrict__ BT,
                                               const void* __restrict__ bias_, void* __restrict__ C_,
                                               const int* __restrict__ flagp, int aF, int oF)
{
  constexpr int N = D_, K = D_;
  constexpr int NT = K/64;
  const int f = *flagp;
  const bool a32 = (aF != 0) && (f != 0);
  const bool o32 = (oF != 0) && (f != 0);
  __shared__ u16 As[2][128*64];      // 32 KB
  __shared__ u16 Bs[2][128*64];      // 32 KB
  const int tid = threadIdx.x;
  const int w = tid>>6, lane = tid&63, g = lane>>4, lr = lane&15;
  const int wm = w>>1, wn = w&1;
  const unsigned flat = blockIdx.y*gridDim.x + blockIdx.x;
  const unsigned cpx  = (gridDim.x*gridDim.y) >> 3;        // 64
  const unsigned swz  = (flat & 7)*cpx + (flat >> 3);
  const int m0 = (int)(swz / gridDim.x) * 128;
  const int n0 = (int)(swz % gridDim.x) * 128;
  const int srow = lane>>3;                        // 0..7
  const int lcol = (lane&7)*8;                     // linear col, u16 units
  const int scol = lcol ^ (srow<<3);               // swizzled col
  const int rsw  = (lr&7)<<3;                      // read-side swizzle (u16)

  const float* Af = (const float*)A_;
  const u16*   Ab = (const u16*)A_;

  #define STAGE_B16(buf, k0_) do{ _Pragma("unroll")                                 \
    for (int jj=0;jj<4;++jj){ const int rb = w*32 + jj*8;                           \
      glds16(BT + (size_t)(n0+rb+srow)*K + (k0_) + scol, (void*)(&Bs[buf][0] + rb*64)); } }while(0)
  #define STAGE_A16(buf, k0_) do{ _Pragma("unroll")                                 \
    for (int jj=0;jj<4;++jj){ const int rb = w*32 + jj*8;                           \
      glds16(Ab + (size_t)(m0+rb+srow)*K + (k0_) + scol, (void*)(&As[buf][0] + rb*64)); } }while(0)
  #define LOAD_A32(k0_) do{ _Pragma("unroll")                                       \
    for (int jj=0;jj<4;++jj){                                                       \
      const float* src = Af + (size_t)(m0 + w*32 + jj*8 + srow)*K + (k0_) + lcol;   \
      ax0[jj] = *(const f32x4*)src; ax1[jj] = *(const f32x4*)(src + 4); } }while(0)
  #define WRITE_A32(buf) do{ _Pragma("unroll")                                      \
    for (int jj=0;jj<4;++jj){ const int rb = w*32 + jj*8; s16x8 pk;                 \
      _Pragma("unroll")                                                             \
      for (int i=0;i<4;++i){ pk[i]=(short)f2b(ax0[jj][i]); pk[4+i]=(short)f2b(ax1[jj][i]); } \
      *(s16x8*)(&As[buf][0] + (rb+srow)*64 + scol) = pk; } }while(0)

  f32x4 ax0[4], ax1[4];
  f32x4 acc[4][4] = {};

  if (a32){ LOAD_A32(0); WRITE_A32(0); } else { STAGE_A16(0, 0); }
  STAGE_B16(0, 0);
  __syncthreads();
  __builtin_amdgcn_sched_barrier(0);

  int cur = 0;
  for (int t=0; t<NT; ++t){
    const bool haveNext = (t+1 < NT);
    if (haveNext){
      if (a32) LOAD_A32((t+1)*64);              // issue early; write after compute
      else     STAGE_A16(cur^1, (t+1)*64);
      STAGE_B16(cur^1, (t+1)*64);
    }
    #pragma unroll
    for (int kk=0;kk<2;++kk){
      s16x8 af[4], bfr[4];
      #pragma unroll
      for (int i=0;i<4;++i) af[i]  = *(const s16x8*)(&As[cur][0] + (wm*64+i*16+lr)*64 + ((kk*32 + g*8) ^ rsw));
      #pragma unroll
      for (int i=0;i<4;++i) bfr[i] = *(const s16x8*)(&Bs[cur][0] + (wn*64+i*16+lr)*64 + ((kk*32 + g*8) ^ rsw));
      #pragma unroll
      for (int mi=0;mi<4;++mi)
        #pragma unroll
        for (int ni=0;ni<4;++ni)
          acc[mi][ni] = __builtin_amdgcn_mfma_f32_16x16x32_bf16(af[mi], bfr[ni], acc[mi][ni], 0,0,0);
    }
    if (haveNext && a32) WRITE_A32(cur^1);      // vmcnt wait lands after MFMAs
    __syncthreads();
    __builtin_amdgcn_sched_barrier(0);          // pin next-iter staging below barrier
    cur ^= 1;
  }
  #pragma unroll
  for (int ni=0;ni<4;++ni){
    const int n = n0 + wn*64 + ni*16 + lr;
    const float bv = f ? ((const float*)bias_)[n] : b2f(((const u16*)bias_)[n]);
    #pragma unroll
    for (int mi=0;mi<4;++mi){
      const int m = m0 + wm*64 + mi*16 + 4*g;
      #pragma unroll
      for (int r=0;r<4;++r){
        const float val = acc[mi][ni][r] + bv;
        if (o32) ((float*)C_)[(size_t)(m+r)*N + n] = val;
        else     ((u16*)C_)[(size_t)(m+r)*N + n] = f2b(val);
      }
    }
  }
  #undef STAGE_B16
  #undef STAGE_A16
  #undef LOAD_A32
  #undef WRITE_A32
}

// ---------------------------------------------------------------------------
// Causal flash attention (R18 version).  grid (S/128, H, B), block 256.
// PAIRED blocks + XCD-chunked remap; K,V staged in LDS (dbuf, XOR swizzle,
// 1 barrier/tile + sched_barrier pin).  Swapped QK^T, lane-local softmax
// (q=lr, FULL online max, expf), f2b pack + 16-shfl gather, ones-MFMA l-sum.
__global__ __launch_bounds__(256) void attn(const u16* __restrict__ Q, const u16* __restrict__ K,
                                            const u16* __restrict__ VT, u16* __restrict__ O)
{
  __shared__ u16  Ks[2][64*128];     // 32 KB, rows kv (256B), swizzled
  __shared__ u16  Vs[2][128*64];     // 32 KB, rows d (128B), swizzled
  u16 (*Ol)[16][136] = (u16(*)[16][136])(&Ks[0][0]);   // epilogue alias, dead staging

  const int tid = threadIdx.x;
  const int w = tid>>6, lane = tid&63, g = lane>>4, lr = lane&15;
  const unsigned flat = blockIdx.x + gridDim.x*(blockIdx.y + gridDim.y*blockIdx.z);
  const unsigned work = (flat & 7)*64u + (flat >> 3);   // bijective on [0,512)
  const int xp = (int)(work & 15);          // pair index 0..15
  const int h  = (int)((work >> 4) & 15);   // head
  const int bz = (int)(work >> 8);          // batch
  const u16* Qb  = Q  + (size_t)bz*S_*D_;
  const u16* Kb  = K  + (size_t)bz*S_*D_;
  const u16* VTb = VT + (size_t)bz*D_*S_;
  u16* Ob = O + (size_t)bz*S_*D_;
  const int sw = (lr&7)<<4;                 // read-side swizzle (bytes)
  const int krow_l = lane>>4, kcol_l = (lane&15)*16;   // K staging lane map
  const int vrow_l = lane>>3, vcol_l = (lane&7)*16;    // V staging lane map

  s16x8 ones;
  #pragma unroll
  for (int i=0;i<8;++i) ones[i] = (short)0x3F80;       // bf16 1.0

  #define STAGE_K(buf, t_) do{ const int kv0s = (t_)*64;                            \
    _Pragma("unroll")                                                               \
    for (int jj=0;jj<4;++jj){ const int j = w*4 + jj; const int r = j*4 + krow_l;   \
      const int cb = kcol_l ^ ((r&7)<<4);                                           \
      glds16(Kb + (size_t)(kv0s + r)*D_ + h*DK_ + (cb>>1), (void*)(&Ks[buf][0] + j*512)); } }while(0)
  #define STAGE_V(buf, t_) do{ const int kv0s = (t_)*64;                            \
    _Pragma("unroll")                                                               \
    for (int jj=0;jj<4;++jj){ const int j = w*4 + jj; const int r = j*8 + vrow_l;   \
      const int cb = vcol_l ^ ((r&7)<<4);                                           \
      glds16(VTb + (size_t)(h*DK_ + r)*S_ + kv0s + (cb>>1), (void*)(&Vs[buf][0] + j*512)); } }while(0)

  for (int qq=0; qq<2; ++qq){
    const int qt = qq ? (int)(S_/64 - 1 - xp) : xp;
    const int q0 = qt*64 + w*16;
    const int nt = qt + 1;

    // Q fragments, pre-scaled by 1/sqrt(dk)
    s16x8 qf[4];
    #pragma unroll
    for (int dc=0;dc<4;++dc){
      s16x8 t = *(const s16x8*)(Qb + (size_t)(q0+lr)*D_ + h*DK_ + dc*32 + g*8);
      #pragma unroll
      for (int i=0;i<8;++i) t[i] = (short)f2b(b2f((u16)t[i]) * SCALE_);
      qf[dc] = t;
    }
    float m_  = -1e30f;              // running max for q-row lr (lane-local)
    float l_q = 0.f;                 // row-sum for q-row lr (lane-local)
    f32x4 accO[8] = {};              // O^T[d=dt*16+4g+r][q=lr], fp32

    STAGE_K(0, 0); STAGE_V(0, 0);
    __syncthreads();
    __builtin_amdgcn_sched_barrier(0);
    int cur = 0;
    for (int t=0;t<nt;++t){
      const int kv0 = t*64;
      const bool lastT = (t == nt-1);
      if (!lastT){ STAGE_K(cur^1, t+1); STAGE_V(cur^1, t+1); }
      // --- QK^T (swapped): sacc[kt][r] = S[q=lr][key=kt*16+4g+r] ---
      const u16* Ksc = &Ks[cur][0];
      f32x4 sacc[4] = {};
      __builtin_amdgcn_s_setprio(1);
      #pragma unroll
      for (int dc=0;dc<4;++dc){
        const int cb = (dc*64 + g*16) ^ sw;
        #pragma unroll
        for (int kt=0;kt<4;++kt){
          s16x8 kf = *(const s16x8*)(Ksc + (kt*16+lr)*128 + (cb>>1));
          sacc[kt] = __builtin_amdgcn_mfma_f32_16x16x32_bf16(kf, qf[dc], sacc[kt], 0,0,0);
        }
      }
      __builtin_amdgcn_s_setprio(0);
      if (lastT){
        #pragma unroll
        for (int kt=0;kt<4;++kt)
          #pragma unroll
          for (int r=0;r<4;++r)
            if (kv0 + kt*16 + 4*g + r > q0 + lr) sacc[kt][r] = -1e30f;
      }
      // --- lane-local online softmax (q=lr), FULL max (no defer) ---
      float tm = sacc[0][0];
      #pragma unroll
      for (int kt=0;kt<4;++kt)
        #pragma unroll
        for (int r=0;r<4;++r) tm = fmaxf(tm, sacc[kt][r]);
      tm = fmaxf(tm, __shfl_xor(tm, 16));
      tm = fmaxf(tm, __shfl_xor(tm, 32));
      const float mn = fmaxf(m_, tm);
      const float sc = __expf(m_ - mn);              // <=1, ==1 when max unchanged
      m_ = mn;
      #pragma unroll
      for (int kt=0;kt<4;++kt)
        #pragma unroll
        for (int r=0;r<4;++r) sacc[kt][r] = __expf(sacc[kt][r] - mn);
      // --- pack P to bf16 pairs (f2b) and gather B-operand fragments ---
      u32 pa[4], pb[4];
      #pragma unroll
      for (int kt=0;kt<4;++kt){
        pa[kt] = pk2(sacc[kt][0], sacc[kt][1]);
        pb[kt] = pk2(sacc[kt][2], sacc[kt][3]);
      }
      const int srcA = lr + 32*(g&1);
      const int srcB = srcA + 16;
      const bool hi = (g >= 2);
      union { s16x8 v; u32 u[4]; } P0, P1;
      {
        u32 a0 = (u32)__shfl((int)pa[0], srcA), a1 = (u32)__shfl((int)pa[1], srcA);
        u32 b0 = (u32)__shfl((int)pb[0], srcA), b1 = (u32)__shfl((int)pb[1], srcA);
        u32 c0 = (u32)__shfl((int)pa[0], srcB), c1 = (u32)__shfl((int)pa[1], srcB);
        u32 d0 = (u32)__shfl((int)pb[0], srcB), d1 = (u32)__shfl((int)pb[1], srcB);
        P0.u[0] = hi ? a1 : a0;  P0.u[1] = hi ? b1 : b0;
        P0.u[2] = hi ? c1 : c0;  P0.u[3] = hi ? d1 : d0;
      }
      {
        u32 a0 = (u32)__shfl((int)pa[2], srcA), a1 = (u32)__shfl((int)pa[3], srcA);
        u32 b0 = (u32)__shfl((int)pb[2], srcA), b1 = (u32)__shfl((int)pb[3], srcA);
        u32 c0 = (u32)__shfl((int)pa[2], srcB), c1 = (u32)__shfl((int)pa[3], srcB);
        u32 d0 = (u32)__shfl((int)pb[2], srcB), d1 = (u32)__shfl((int)pb[3], srcB);
        P1.u[0] = hi ? a1 : a0;  P1.u[1] = hi ? b1 : b0;
        P1.u[2] = hi ? c1 : c0;  P1.u[3] = hi ? d1 : d0;
      }
      const s16x8 pf0 = P0.v, pf1 = P1.v;
      // --- l-sum via ones-MFMA (same quantized P as PV) ---
      f32x4 ls = {};
      ls = __builtin_amdgcn_mfma_f32_16x16x32_bf16(ones, pf0, ls, 0,0,0);
      ls = __builtin_amdgcn_mfma_f32_16x16x32_bf16(ones, pf1, ls, 0,0,0);
      l_q = l_q*sc + ls[0];
      if (__any(sc != 1.0f)){
        #pragma unroll
        for (int dt=0;dt<8;++dt)
          #pragma unroll
          for (int r=0;r<4;++r) accO[dt][r] *= sc;
      }
      // --- PV: O^T += V^T @ P^T (V from LDS) ---
      const u16* Vsc = &Vs[cur][0];
      const int cb0 = (g*16) ^ sw;
      const int cb1 = (64 + g*16) ^ sw;
      __builtin_amdgcn_s_setprio(1);
      #pragma unroll
      for (int dt=0;dt<8;++dt){
        s16x8 vf0 = *(const s16x8*)(Vsc + (dt*16+lr)*64 + (cb0>>1));
        accO[dt] = __builtin_amdgcn_mfma_f32_16x16x32_bf16(vf0, pf0, accO[dt], 0,0,0);
        s16x8 vf1 = *(const s16x8*)(Vsc + (dt*16+lr)*64 + (cb1>>1));
        accO[dt] = __builtin_amdgcn_mfma_f32_16x16x32_bf16(vf1, pf1, accO[dt], 0,0,0);
      }
      __builtin_amdgcn_s_setprio(0);
      __syncthreads();          // staged t+1 visible; buffers swappable
      __builtin_amdgcn_sched_barrier(0);   // pin next-iter staging below barrier
      cur ^= 1;
    }
    // --- epilogue: transpose via LDS (aliases dead K staging), store ---
    const float linv = 1.0f / l_q;
    #pragma unroll
    for (int dt=0;dt<8;++dt)
      #pragma unroll
      for (int r=0;r<4;++r)
        Ol[w][lr][dt*16 + 4*g + r] = f2b(accO[dt][r] * linv);
    __syncthreads();
    #pragma unroll
    for (int p=0;p<4;++p){
      const int ql = p*4 + g;
      s16x8 ov = *(const s16x8*)(&Ol[w][ql][0] + lr*8);
      *(s16x8*)(Ob + (size_t)(q0+ql)*D_ + h*DK_ + lr*8) = ov;
    }
    __syncthreads();            // Ol reads done before next phase's STAGE_K
    __builtin_amdgcn_sched_barrier(0);
  }
  #undef STAGE_K
  #undef STAGE_V
}

// ---------------------------------------------------------------------------
extern "C" void kernel_launch(void* const* d_in, const int* in_sizes, int n_in,
                              void* d_out, int out_size, void* d_ws, size_t ws_size,
                              hipStream_t stream)
{
  const void* q   = d_in[0];
  const void* k   = d_in[1];
  const void* v   = d_in[2];
  const void* wq  = d_in[3];  const void* bq = d_in[4];
  const void* laq = d_in[5];  const void* lbq= d_in[6];
  const void* wk  = d_in[7];  const void* bk = d_in[8];
  const void* lak = d_in[9];  const void* lbk= d_in[10];
  const void* wv  = d_in[11]; const void* bv = d_in[12];
  const void* lav = d_in[13]; const void* lbv= d_in[14];
  const void* wo  = d_in[15]; const void* bo = d_in[16];
  const void* lao = d_in[17]; const void* lbo= d_in[18];

  char* ws = (char*)d_ws;
  int* flag = (int*)ws;
  char* base = ws + 256;
  const size_t MB = 1u<<20;
  u16* W   = (u16*)(base);            //  8 MiB, reused for each effW^T
  u16* Qb  = (u16*)(base +  8*MB);    // 16 MiB
  u16* Kb  = (u16*)(base + 24*MB);    // 16 MiB
  u16* Vb  = (u16*)(base + 40*MB);    // 16 MiB
  u16* VTb = (u16*)(base + 56*MB);    // 16 MiB
  u16* Ob  = Vb;                      // V dead after transpose
  u16* X   = (u16*)(base + 72*MB);    // 16 MiB, converted A (reused Q->K->V)
  const bool useCvt = ws_size >= (size_t)(88*MB + 256);

  dim3 blk(256);
  dim3 gW(D_/64, D_/64);
  dim3 gG(D_/128, MROWS/128);
  const int nElems = MROWS * D_;      // 8M elements per activation
  detect32<<<1, blk, 0, stream>>>((const unsigned*)q, flag);
  prep_wt<<<gW, blk, 0, stream>>>(wq, laq, lbq, W, flag);
  if (useCvt){
    cvt_bf16<<<2048, blk, 0, stream>>>(q, X, flag, nElems);
    gemm_bt<<<gG, blk, 0, stream>>>(X, W, bq, Qb, flag, 0, 0);
  } else {
    gemm_bt<<<gG, blk, 0, stream>>>(q, W, bq, Qb, flag, 1, 0);
  }
  prep_wt<<<gW, blk, 0, stream>>>(wk, lak, lbk, W, flag);
  if (useCvt){
    cvt_bf16<<<2048, blk, 0, stream>>>(k, X, flag, nElems);
    gemm_bt<<<gG, blk, 0, stream>>>(X, W, bk, Kb, flag, 0, 0);
  } else {
    gemm_bt<<<gG, blk, 0, stream>>>(k, W, bk, Kb, flag, 1, 0);
  }
  prep_wt<<<gW, blk, 0, stream>>>(wv, lav, lbv, W, flag);
  if (useCvt){
    cvt_bf16<<<2048, blk, 0, stream>>>(v, X, flag, nElems);
    gemm_bt<<<gG, blk, 0, stream>>>(X, W, bv, Vb, flag, 0, 0);
  } else {
    gemm_bt<<<gG, blk, 0, stream>>>(v, W, bv, Vb, flag, 1, 0);
  }
  transpose_v<<<dim3(S_/64, D_/64, B_), blk, 0, stream>>>(Vb, VTb);
  attn<<<dim3(S_/128, H_, B_), blk, 0, stream>>>(Qb, Kb, VTb, Ob);
  prep_wt<<<gW, blk, 0, stream>>>(wo, lao, lbo, W, flag);
  gemm_bt<<<gG, blk, 0, stream>>>(Ob, W, bo, d_out, flag, 0, 1);
}